// Round 6
// baseline (1790.790 us; speedup 1.0000x reference)
//
#include <hip/hip_runtime.h>
#include <hip/hip_bf16.h>
#include <hip/hip_cooperative_groups.h>

namespace cg = cooperative_groups;

// TorchMD_GN_Ext R18: cooperative fusion of the 6-layer loop on R17.
//  - layers_k: one cooperative kernel (grid 1024x256, launch_bounds(256,4)) runs
//    all 6 x (filter-scatter -> node-update) phases with grid.sync() (11 syncs,
//    replacing 11 dispatch boundaries)
//  - per-block window metadata (seg_prep) computed ONCE, reused across 6 layers;
//    kidx/src held in registers (statically-indexed unrolled window loop)
//  - host fallback to the R17 12-dispatch path if cooperative launch is rejected
//  8 kernel dispatches + 1 memset (coop path).

#define NATOMS 10000
#define NEDGES 320000
#define HC 128
#define RBF 50
#define NLAY 6
#define MAXZ_ 100
#define NK 8192
#define EG 1250                     // (NEDGES+255)/256
#define TBGRID (7 * (NK / 64))      // 896
#define EGRID (NEDGES / 64)         // 5000 worst case; blocks early-exit past Eact
#define YGRID ((NATOMS + 63) / 64)  // 157
#define UGRID (NATOMS / 16)         // 625 (NATOMS % 16 == 0)
#define COOPGRID 1024               // 4 blocks/CU x 256 CU guaranteed co-resident
#define MAXW 5                      // ceil(5000 / 1024) worst-case windows/block

typedef __hip_bfloat16 bf16;
typedef __attribute__((ext_vector_type(8))) short bf8v;
typedef __attribute__((ext_vector_type(4))) float f4v;
typedef __attribute__((ext_vector_type(4))) int i4v;

__device__ __forceinline__ float b2f(bf16 v) { return __bfloat162float(v); }
__device__ __forceinline__ bf16  f2b(float v) { return __float2bfloat16(v); }
__device__ __forceinline__ short f2s(float v) { bf16 h = f2b(v); return *(short*)&h; }
__device__ __forceinline__ float s2f(unsigned short s) {
    return __int_as_float(((int)s) << 16);
}
__device__ __forceinline__ float silu(float v) {
    return v * __builtin_amdgcn_rcpf(1.0f + __expf(-v));
}
__device__ __forceinline__ int isf_of(const int* flagp) {
    return (__int_as_float(flagp[0]) > 1.0e4f) ? 1 : 0;
}

template<int ISF>
__device__ __forceinline__ float LD(const void* p, size_t i) {
    if (ISF) return ((const float*)p)[i];
    return b2f(((const bf16*)p)[i]);
}

// 8 consecutive f32 -> bf8v via two dwordx4 loads (same rounding as scalar path)
__device__ __forceinline__ bf8v f32x8_to_b(const float* p) {
    f4v v0 = *(const f4v*)p;
    f4v v1 = *(const f4v*)(p + 4);
    bf8v r;
    r[0] = f2s(v0[0]); r[1] = f2s(v0[1]); r[2] = f2s(v0[2]); r[3] = f2s(v0[3]);
    r[4] = f2s(v1[0]); r[5] = f2s(v1[1]); r[6] = f2s(v1[2]); r[7] = f2s(v1[3]);
    return r;
}
template<int ISF>
__device__ __forceinline__ bf8v LD8(const void* p, size_t i) {
    if (ISF) return f32x8_to_b((const float*)p + i);
    return *(const bf8v*)((const bf16*)p + i);
}

__device__ __forceinline__ int clampN(int v) {
    return v < 0 ? 0 : (v >= NATOMS ? NATOMS - 1 : v);
}

template<int ISF>
__device__ __forceinline__ float edge_d(const int* __restrict__ ei,
                                        const void* __restrict__ pos, int e,
                                        int* sOut, int* tOut) {
    int s = clampN(ei[e]);
    int t = clampN(ei[NEDGES + e]);
    *sOut = s; *tOut = t;
    float dx = LD<ISF>(pos, (size_t)s * 3 + 0) - LD<ISF>(pos, (size_t)t * 3 + 0);
    float dy = LD<ISF>(pos, (size_t)s * 3 + 1) - LD<ISF>(pos, (size_t)t * 3 + 1);
    float dz = LD<ISF>(pos, (size_t)s * 3 + 2) - LD<ISF>(pos, (size_t)t * 3 + 2);
    float d = sqrtf(dx * dx + dy * dy + dz * dz + 1e-12f);
    if (d != d) d = 1e30f;
    return d;
}

// ---------------- dtype probe ----------------
__global__ void probe_k(const void* pos, int* flag) {
    int i = blockIdx.x * 256 + threadIdx.x;
    float v = 0.0f;
    if (i < NATOMS * 3) {
        v = fabsf(b2f(((const bf16*)pos)[i]));
        if (v != v) v = 1e30f;
    }
    #pragma unroll
    for (int off = 32; off > 0; off >>= 1)
        v = fmaxf(v, __shfl_xor(v, off, 64));
    if ((threadIdx.x & 63) == 0) atomicMax(flag, __float_as_int(v));
}

// ------- histogram of ACTIVE (d<5) edges + d cache -------
template<int ISF>
__device__ __forceinline__ void histd_body(int b, int tid, const int* __restrict__ ei,
                                           const void* __restrict__ pos,
                                           int* __restrict__ counts,
                                           float* __restrict__ d_raw) {
    int e = b * 256 + tid;
    if (e >= NEDGES) return;
    int s, t;
    float d = edge_d<ISF>(ei, pos, e, &s, &t);
    d_raw[e] = d;
    if (d < 5.0f) atomicAdd(&counts[t], 1);
}

// ---------------- mega pack/convert ----------------
template<int ISF>
__device__ void packB_at(int t, const void* src, int K, int ksteps, size_t perLsrc,
                         size_t perLdst, int L, bf16* dst) {
    if (t >= L * 8 * ksteps * 64) return;
    int lane = t & 63;
    int t2 = t >> 6;
    int ks = t2 % ksteps;
    int t3 = t2 / ksteps;
    int nt = t3 & 7;
    int l  = t3 >> 3;
    int quad = lane >> 4, lc = lane & 15;
    int col = nt * 16 + lc;
    for (int j = 0; j < 8; j++) {
        int k = ks * 32 + quad * 8 + j;
        float v = (k < K) ? LD<ISF>(src, (size_t)l * perLsrc + (size_t)k * 128 + col) : 0.0f;
        dst[(size_t)l * perLdst + ((size_t)((nt * ksteps + ks) * 64 + lane)) * 8 + j] = f2b(v);
    }
}
template<int ISF>
__device__ void packB24_at(int t, const void* w2, const void* cw1, const void* cw2,
                           const void* lw, bf16* w2p, bf16* cw1p, bf16* cw2p, bf16* lwp) {
    if (t >= 24 * 8 * 4 * 64) return;
    int lane = t & 63;
    int t2 = t >> 6;
    int ks = t2 & 3;
    int t3 = t2 >> 2;
    int nt = t3 & 7;
    int m  = t3 >> 3;
    int which = m / NLAY, li = m % NLAY;
    const void* src = which == 0 ? w2 : which == 1 ? cw1 : which == 2 ? cw2 : lw;
    bf16* dst = which == 0 ? w2p : which == 1 ? cw1p : which == 2 ? cw2p : lwp;
    int quad = lane >> 4, lc = lane & 15;
    int col = nt * 16 + lc;
    #pragma unroll
    for (int j = 0; j < 8; j++) {
        int k = ks * 32 + quad * 8 + j;
        float v = LD<ISF>(src, (size_t)li * 16384 + (size_t)k * 128 + col);
        dst[(size_t)li * 16384 + ((size_t)((nt * 4 + ks) * 64 + lane)) * 8 + j] = f2b(v);
    }
}
template<int ISF>
__device__ void cvts_at(int i, const void* means, const void* betas, const void* bp,
                        const void* bc, const void* b1, const void* b2,
                        const void* cb2, const void* lb,
                        float* meanscv, float* betascv, float* bpcv, float* bccv,
                        float* b1cv, float* b2cv, float* cb2cv, float* lbcv) {
    if      (i < 50)   meanscv[i]        = LD<ISF>(means, i);
    else if (i < 100)  betascv[i - 50]   = LD<ISF>(betas, i - 50);
    else if (i < 228)  bpcv[i - 100]     = LD<ISF>(bp, i - 100);
    else if (i < 356)  bccv[i - 228]     = LD<ISF>(bc, i - 228);
    else if (i < 1124) b1cv[i - 356]     = LD<ISF>(b1, i - 356);
    else if (i < 1892) b2cv[i - 1124]    = LD<ISF>(b2, i - 1124);
    else if (i < 2660) cb2cv[i - 1892]   = LD<ISF>(cb2, i - 1892);
    else if (i < 3428) lbcv[i - 2660]    = LD<ISF>(lb, i - 2660);
}
template<int ISF>
__device__ void packall_body(int b, int tid, const void* Wp, const void* Wc, const void* W1,
                             const void* W2, const void* cW1, const void* cW2,
                             const void* lW, const void* means, const void* betas,
                             const void* bp, const void* bc, const void* b1,
                             const void* b2, const void* cb2, const void* lb,
                             const void* nbremb,
                             bf16* wpp, bf16* wcp, bf16* w1p, bf16* w2p, bf16* cw1p,
                             bf16* cw2p, bf16* lwp, float* meanscv, float* betascv,
                             float* bpcv, float* bccv, float* b1cv, float* b2cv,
                             float* cb2cv, float* lbcv, bf16* nbrembbf) {
    if (b < 4)        packB_at<ISF>(b * 256 + tid, Wp, RBF, 2, 6400, 8192, 1, wpp);
    else if (b < 20)  packB_at<ISF>((b - 4) * 256 + tid, Wc, 256, 8, 32768, 32768, 1, wcp);
    else if (b < 44)  packB_at<ISF>((b - 20) * 256 + tid, W1, RBF, 2, 6400, 8192, NLAY, w1p);
    else if (b < 236) packB24_at<ISF>((b - 44) * 256 + tid, W2, cW1, cW2, lW,
                                      w2p, cw1p, cw2p, lwp);
    else if (b < 250) cvts_at<ISF>((b - 236) * 256 + tid, means, betas, bp, bc, b1, b2,
                                   cb2, lb, meanscv, betascv, bpcv, bccv,
                                   b1cv, b2cv, cb2cv, lbcv);
    else {
        int i = (b - 250) * 256 + tid;
        if (i < MAXZ_ * HC) nbrembbf[i] = f2b(LD<ISF>(nbremb, i));
    }
}

// -------- setup1: histd (blocks 0..1249) + packall (blocks 1250..1549) --------
__global__ __launch_bounds__(256)
void setup1_k(const int* ei, const void* pos, const int* flagp,
              int* counts, float* d_raw,
              const void* Wp, const void* Wc, const void* W1,
              const void* W2, const void* cW1, const void* cW2,
              const void* lW, const void* means, const void* betas,
              const void* bp, const void* bc, const void* b1,
              const void* b2, const void* cb2, const void* lb,
              const void* nbremb,
              bf16* wpp, bf16* wcp, bf16* w1p, bf16* w2p, bf16* cw1p,
              bf16* cw2p, bf16* lwp, float* meanscv, float* betascv,
              float* bpcv, float* bccv, float* b1cv, float* b2cv,
              float* cb2cv, float* lbcv, bf16* nbrembbf) {
    int b = blockIdx.x, tid = threadIdx.x;
    int isf = isf_of(flagp);
    if (b < EG) {
        if (isf) histd_body<1>(b, tid, ei, pos, counts, d_raw);
        else     histd_body<0>(b, tid, ei, pos, counts, d_raw);
    } else {
        b -= EG;
        if (isf) packall_body<1>(b, tid, Wp, Wc, W1, W2, cW1, cW2, lW, means, betas,
                                 bp, bc, b1, b2, cb2, lb, nbremb, wpp, wcp,
                                 w1p, w2p, cw1p, cw2p, lwp, meanscv, betascv,
                                 bpcv, bccv, b1cv, b2cv, cb2cv, lbcv, nbrembbf);
        else     packall_body<0>(b, tid, Wp, Wc, W1, W2, cW1, cW2, lW, means, betas,
                                 bp, bc, b1, b2, cb2, lb, nbremb, wpp, wcp,
                                 w1p, w2p, cw1p, cw2p, lwp, meanscv, betascv,
                                 bpcv, bccv, b1cv, b2cv, cb2cv, lbcv, nbrembbf);
    }
}

// ---------------- scan (one-pass: 10 elems/thread) ----------------
__global__ void scan_k(const int* __restrict__ counts, int* __restrict__ rowptr,
                       int* __restrict__ cursor) {
    __shared__ int wsum[16];
    int tid = threadIdx.x, lane = tid & 63, w = tid >> 6;
    int base = tid * 10;
    int v[10];
    int s = 0;
    #pragma unroll
    for (int j = 0; j < 10; j++) {
        int i = base + j;
        int c = (i < NATOMS) ? counts[i] : 0;
        v[j] = c; s += c;
    }
    int si = s;
    #pragma unroll
    for (int off = 1; off < 64; off <<= 1) {
        int t = __shfl_up(si, off, 64);
        if (lane >= off) si += t;
    }
    if (lane == 63) wsum[w] = si;
    __syncthreads();
    if (w == 0 && lane < 16) {
        int t = wsum[lane];
        int s2 = t;
        #pragma unroll
        for (int off = 1; off < 16; off <<= 1) {
            int u = __shfl_up(s2, off, 64);
            if (lane >= off) s2 += u;
        }
        wsum[lane] = s2 - t;   // exclusive wave prefix
    }
    __syncthreads();
    int run = wsum[w] + si - s;
    #pragma unroll
    for (int j = 0; j < 10; j++) {
        int i = base + j;
        if (i < NATOMS) {
            cursor[i] = run;
            run += v[j];
            rowptr[i + 1] = run;
        }
    }
    if (tid == 0) rowptr[0] = 0;
}

// ---------------- MFMA helpers ----------------
#define MFMA(a, b, c) __builtin_amdgcn_mfma_f32_16x16x32_bf16((a), (b), (c), 0, 0, 0)

// ---------- permgeom body (blocks 0..1249 of setup2) ----------
__device__ __forceinline__ void permgeom_body(int b, int tid, const int* __restrict__ ei,
                                              const float* __restrict__ d_raw,
                                              int* __restrict__ cursor,
                                              int* __restrict__ kidx_s,
                                              int* __restrict__ src_s,
                                              int* __restrict__ dst_s) {
    int e = b * 256 + tid;
    if (e >= NEDGES) return;
    float d = d_raw[e];
    if (d >= 5.0f) return;
    int s = clampN(ei[e]);
    int t = clampN(ei[NEDGES + e]);
    int p = atomicAdd(&cursor[t], 1);
    float ed = __expf(-d);
    float pos = fminf(fmaxf(ed * (float)(NK - 1) + 0.5f, 0.0f), (float)(NK - 1));
    kidx_s[p] = (int)pos;
    src_s[p] = s;
    dst_s[p] = t;
}

// ---------- tabbuild body (blocks 1250.. of setup2) ----------
__device__ __forceinline__ void tabbuild_body(int bb, int tid,
                const bf16* __restrict__ wpp, const float* __restrict__ bpcv,
                const bf16* __restrict__ w1p, const float* __restrict__ b1cv,
                const bf16* __restrict__ w2p, const float* __restrict__ b2cv,
                const float* __restrict__ meanscv, const float* __restrict__ betascv,
                bf16* __restrict__ Tb) {
    __shared__ bf16 hid[64][136];
    __shared__ float csh[64], edsh[64];
    int f = bb >> 7, kb = bb & 127;
    int base = kb * 64;
    int wave = tid >> 6, lane = tid & 63, quad = lane >> 4, lc = lane & 15;
    if (tid < 64) {
        float ed = (float)(base + tid) * (1.0f / (NK - 1));
        float d = -logf(fmaxf(ed, 1e-30f));
        float C = (d < 5.0f) ? 0.5f * (__cosf(d * 0.6283185307f) + 1.0f) : 0.0f;
        csh[tid] = C; edsh[tid] = ed;
    }
    __syncthreads();
    float edi = edsh[wave * 16 + lc], Ci = csh[wave * 16 + lc];
    bf8v af[2];
    #pragma unroll
    for (int ks = 0; ks < 2; ks++) {
        #pragma unroll
        for (int j = 0; j < 8; j++) {
            int r = ks * 32 + quad * 8 + j;
            float v = 0.0f;
            if (r < RBF) { float u = edi - meanscv[r]; v = Ci * __expf(-betascv[r] * u * u); }
            af[ks][j] = f2s(v);
        }
    }
    f4v zero = {0.f, 0.f, 0.f, 0.f};
    f4v acc[8];
    #pragma unroll
    for (int nt = 0; nt < 8; nt++) acc[nt] = zero;
    const bf16* w1b = (f == 0) ? wpp : w1p + (size_t)(f - 1) * 8192;
    #pragma unroll
    for (int nt = 0; nt < 8; nt++)
        #pragma unroll
        for (int ks = 0; ks < 2; ks++) {
            bf8v b = *(const bf8v*)(w1b + ((nt * 2 + ks) * 64 + lane) * 8);
            acc[nt] = MFMA(af[ks], b, acc[nt]);
        }
    if (f == 0) {
        #pragma unroll
        for (int nt = 0; nt < 8; nt++) {
            int n = nt * 16 + lc;
            float bb2 = bpcv[n];
            #pragma unroll
            for (int r = 0; r < 4; r++) {
                int row = wave * 16 + quad * 4 + r;
                Tb[(size_t)(base + row) * HC + n] = f2b((acc[nt][r] + bb2) * csh[row]);
            }
        }
        return;
    }
    int l = f - 1;
    #pragma unroll
    for (int nt = 0; nt < 8; nt++) {
        int n = nt * 16 + lc;
        float bb2 = b1cv[l * HC + n];
        #pragma unroll
        for (int r = 0; r < 4; r++)
            hid[wave * 16 + quad * 4 + r][n] = f2b(silu(acc[nt][r] + bb2));
    }
    __syncthreads();
    bf8v a2[4];
    #pragma unroll
    for (int ks = 0; ks < 4; ks++)
        a2[ks] = *(const bf8v*)&hid[wave * 16 + lc][ks * 32 + quad * 8];
    f4v acc2[8];
    #pragma unroll
    for (int nt = 0; nt < 8; nt++) acc2[nt] = zero;
    const bf16* w2b = w2p + (size_t)l * 16384;
    #pragma unroll
    for (int nt = 0; nt < 8; nt++)
        #pragma unroll
        for (int ks = 0; ks < 4; ks++) {
            bf8v b = *(const bf8v*)(w2b + ((nt * 4 + ks) * 64 + lane) * 8);
            acc2[nt] = MFMA(a2[ks], b, acc2[nt]);
        }
    #pragma unroll
    for (int nt = 0; nt < 8; nt++) {
        int n = nt * 16 + lc;
        float bb2 = b2cv[l * HC + n];
        #pragma unroll
        for (int r = 0; r < 4; r++) {
            int row = wave * 16 + quad * 4 + r;
            Tb[((size_t)f * NK + base + row) * HC + n] = f2b((acc2[nt][r] + bb2) * csh[row]);
        }
    }
}

// -------- setup2: permgeom (blocks 0..1249) + tabbuild (blocks 1250..2145) --------
__global__ __launch_bounds__(256)
void setup2_k(const int* ei, const float* d_raw, int* cursor,
              int* kidx_s, int* src_s, int* dst_s,
              const bf16* wpp, const float* bpcv,
              const bf16* w1p, const float* b1cv,
              const bf16* w2p, const float* b2cv,
              const float* meanscv, const float* betascv, bf16* Tb) {
    int b = blockIdx.x, tid = threadIdx.x;
    if (b < EG) permgeom_body(b, tid, ei, d_raw, cursor, kidx_s, src_s, dst_s);
    else        tabbuild_body(b - EG, tid, wpp, bpcv, w1p, b1cv, w2p, b2cv,
                              meanscv, betascv, Tb);
}

// ---------------- segment helpers ----------------
__device__ __forceinline__ void seg_prep(const int* __restrict__ dst_s, int i0, int tid,
                                         int* ddst, int* slot_s, int* distinct_s,
                                         int* nseg_s) {
    if (tid < 64) {
        int d = dst_s[i0 + tid];
        ddst[tid] = d;
        int dprev = __shfl_up(d, 1, 64);
        int flag = (tid == 0 || d != dprev) ? 1 : 0;
        int s = flag;
        #pragma unroll
        for (int off = 1; off < 64; off <<= 1) {
            int t = __shfl_up(s, off, 64);
            if (tid >= off) s += t;
        }
        slot_s[tid] = s - 1;
        if (flag) distinct_s[s - 1] = d;
        if (tid == 63) *nseg_s = s;
    }
}

__device__ __forceinline__ void seg_mfma(const bf16 (*mvT)[72], const int* ddst,
                                         const int* slot_s, const int* distinct_s,
                                         int nseg, float* __restrict__ out, int tid) {
    int wave = tid >> 6, lane = tid & 63, quad = lane >> 4, lc = lane & 15;
    if (nseg <= 16) {
        bf8v sa[2];
        #pragma unroll
        for (int ks = 0; ks < 2; ks++) {
            int k0 = ks * 32 + quad * 8;
            i4v s0 = *(const i4v*)&slot_s[k0];
            i4v s1 = *(const i4v*)&slot_s[k0 + 4];
            #pragma unroll
            for (int j = 0; j < 4; j++) {
                sa[ks][j]     = (s0[j] == lc) ? (short)0x3F80 : (short)0;
                sa[ks][j + 4] = (s1[j] == lc) ? (short)0x3F80 : (short)0;
            }
        }
        f4v z4 = {0.f, 0.f, 0.f, 0.f};
        f4v sacc[2] = {z4, z4};
        #pragma unroll
        for (int nt = 0; nt < 2; nt++)
            #pragma unroll
            for (int ks = 0; ks < 2; ks++) {
                bf8v b = *(const bf8v*)&mvT[wave * 32 + nt * 16 + lc][ks * 32 + quad * 8];
                sacc[nt] = MFMA(sa[ks], b, sacc[nt]);
            }
        #pragma unroll
        for (int nt = 0; nt < 2; nt++)
            #pragma unroll
            for (int r = 0; r < 4; r++) {
                int sl = quad * 4 + r;
                if (sl < nseg) {
                    int atom = distinct_s[sl];
                    int n = wave * 32 + nt * 16 + lc;
                    float v = sacc[nt][r];
                    if (sl == 0 || sl == nseg - 1)
                        atomicAdd(&out[(size_t)atom * HC + n], v);
                    else
                        out[(size_t)atom * HC + n] = v;
                }
            }
    } else {
        int col = tid & 127;
        int base = (tid >> 7) * 32;
        int cur = ddst[base];
        float s = 0.0f;
        bool first = true;
        for (int e = base; e < base + 32; e++) {
            int dn = ddst[e];
            if (dn != cur) {
                if (first) atomicAdd(&out[(size_t)cur * HC + col], s);
                else out[(size_t)cur * HC + col] = s;
                first = false; cur = dn; s = 0.0f;
            }
            s += b2f(mvT[col][e]);
        }
        atomicAdd(&out[(size_t)cur * HC + col], s);
    }
}

// ---------------- neighbor edges ----------------
__global__ __launch_bounds__(256)
void nbr_tab_k(const int* __restrict__ rowptr,
               const int* __restrict__ kidx_s, const int* __restrict__ src_s,
               const int* __restrict__ dst_s, const int* __restrict__ z,
               const bf16* __restrict__ nbrembbf, const bf16* __restrict__ Tb,
               float* __restrict__ msg) {
    __shared__ bf16 mvT[128][72];
    __shared__ int ddst[64], slot_s[64], distinct_s[64];
    __shared__ int nseg_s;
    int i0 = blockIdx.x * 64;
    if (i0 >= rowptr[NATOMS]) return;
    int tid = threadIdx.x;
    seg_prep(dst_s, i0, tid, ddst, slot_s, distinct_s, &nseg_s);
    int row = tid & 63, c0 = (tid >> 6) * 32;
    int e = i0 + row;
    int s = src_s[e];
    float msk = (s != dst_s[e]) ? 1.0f : 0.0f;
    int k = kidx_s[e];
    const bf8v* tp = (const bf8v*)(Tb + (size_t)k * HC + c0);
    bf8v tv[4];
    #pragma unroll
    for (int g = 0; g < 4; g++) tv[g] = tp[g];
    int zz = z[s]; zz = zz < 0 ? 0 : (zz >= MAXZ_ ? MAXZ_ - 1 : zz);
    const bf8v* ep = (const bf8v*)(nbrembbf + (size_t)zz * HC + c0);
    bf8v ev[4];
    #pragma unroll
    for (int g = 0; g < 4; g++) ev[g] = ep[g];
    #pragma unroll
    for (int g = 0; g < 4; g++)
        #pragma unroll
        for (int m = 0; m < 8; m++) {
            float v = s2f((unsigned short)tv[g][m]) * msk *
                      s2f((unsigned short)ev[g][m]);
            mvT[c0 + g * 8 + m][row] = f2b(v);
        }
    __syncthreads();
    seg_mfma(mvT, ddst, slot_s, distinct_s, nseg_s, msg, tid);
}

// ---------------- combine (prep fused) ----------------
template<int ISF>
__device__ void combine_body(const int* __restrict__ z, const void* __restrict__ emb,
                             const float* __restrict__ msg, const bf16* __restrict__ wcp,
                             const float* __restrict__ bccv, const bf16* __restrict__ cw1b,
                             float* __restrict__ x, bf16* __restrict__ xb,
                             bf16* __restrict__ ybf) {
    __shared__ bf16 srow[64][136];
    int tid = threadIdx.x;
    int wave = tid >> 6, lane = tid & 63, quad = lane >> 4, lc = lane & 15;
    int m0 = blockIdx.x * 64;
    int arow = m0 + wave * 16 + lc;
    int rowc = arow < NATOMS ? arow : NATOMS - 1;
    int zz = z[rowc]; zz = zz < 0 ? 0 : (zz >= MAXZ_ ? MAXZ_ - 1 : zz);
    bf8v af[8];
    #pragma unroll
    for (int ks = 0; ks < 4; ks++)
        af[ks] = LD8<ISF>(emb, (size_t)zz * HC + ks * 32 + quad * 8);
    #pragma unroll
    for (int ks = 4; ks < 8; ks++)
        af[ks] = f32x8_to_b(msg + (size_t)rowc * HC + (ks - 4) * 32 + quad * 8);
    f4v zero = {0.f, 0.f, 0.f, 0.f};
    f4v acc[8];
    #pragma unroll
    for (int nt = 0; nt < 8; nt++) acc[nt] = zero;
    #pragma unroll
    for (int nt = 0; nt < 8; nt++)
        #pragma unroll
        for (int ks = 0; ks < 8; ks++) {
            bf8v b = *(const bf8v*)(wcp + ((nt * 8 + ks) * 64 + lane) * 8);
            acc[nt] = MFMA(af[ks], b, acc[nt]);
        }
    #pragma unroll
    for (int nt = 0; nt < 8; nt++) {
        int n = nt * 16 + lc;
        float bb = bccv[n];
        #pragma unroll
        for (int r = 0; r < 4; r++) {
            int row = m0 + wave * 16 + quad * 4 + r;
            float v = acc[nt][r] + bb;
            bf16 vb = f2b(v);
            srow[wave * 16 + quad * 4 + r][n] = vb;
            if (row < NATOMS) {
                x[(size_t)row * HC + n] = v;
                xb[(size_t)row * HC + n] = vb;
            }
        }
    }
    __syncthreads();
    bf8v a3[4];
    #pragma unroll
    for (int ks = 0; ks < 4; ks++)
        a3[ks] = *(const bf8v*)&srow[wave * 16 + lc][ks * 32 + quad * 8];
    f4v acc3[8];
    #pragma unroll
    for (int nt = 0; nt < 8; nt++) acc3[nt] = zero;
    #pragma unroll
    for (int nt = 0; nt < 8; nt++)
        #pragma unroll
        for (int ks = 0; ks < 4; ks++) {
            bf8v b = *(const bf8v*)(cw1b + ((nt * 4 + ks) * 64 + lane) * 8);
            acc3[nt] = MFMA(a3[ks], b, acc3[nt]);
        }
    #pragma unroll
    for (int nt = 0; nt < 8; nt++) {
        int n = nt * 16 + lc;
        #pragma unroll
        for (int r = 0; r < 4; r++) {
            int row = m0 + wave * 16 + quad * 4 + r;
            if (row < NATOMS) ybf[(size_t)row * HC + n] = f2b(acc3[nt][r]);
        }
    }
}
__global__ __launch_bounds__(256)
void combine_k(const int* z, const void* emb, const float* msg, const bf16* wcp,
               const float* bccv, const bf16* cw1b, const int* flagp,
               float* x, bf16* xb, bf16* ybf) {
    if (isf_of(flagp)) combine_body<1>(z, emb, msg, wcp, bccv, cw1b, x, xb, ybf);
    else               combine_body<0>(z, emb, msg, wcp, bccv, cw1b, x, xb, ybf);
}

// ============ cooperative 6-layer kernel (filt + upd fused, 11 grid syncs) ============
__global__ __launch_bounds__(256, 4)
void layers_k(const int* __restrict__ rowptr, const int* __restrict__ kidx_s,
              const int* __restrict__ src_s, const int* __restrict__ dst_s,
              const bf16* __restrict__ Tb, float* __restrict__ msum,
              const bf16* __restrict__ cw2p, const float* __restrict__ cb2cv,
              const bf16* __restrict__ lwp, const float* __restrict__ lbcv,
              const bf16* __restrict__ cw1p, float* __restrict__ x,
              bf16* __restrict__ xb, bf16* __restrict__ ybf,
              void* out, const int* flagp) {
    cg::grid_group grid = cg::this_grid();
    __shared__ bf16 mvT[128][72];
    __shared__ int ddstM[MAXW][64], slotM[MAXW][64], distM[MAXW][64];
    __shared__ int nsegM[MAXW];
    __shared__ bf16 srow[16][136];
    int tid = threadIdx.x, bid = blockIdx.x;
    int Eact = rowptr[NATOMS];
    int isf = isf_of(flagp);
    f4v zero = {0.f, 0.f, 0.f, 0.f};
    int wv = tid >> 6, lane = tid & 63, quad = lane >> 4, lc = lane & 15;
    int row = lane, c0 = wv * 32;
    int m0 = bid * 16;

    // ---- pre-phase: per-window seg metadata (once, reused across 6 layers);
    //      kidx/src in regs (fully unrolled => static indexing) ----
    int kreg[MAXW], sreg[MAXW];
    #pragma unroll
    for (int i = 0; i < MAXW; i++) {
        int w = bid + i * COOPGRID;
        bool act = (w * 64 < Eact);               // block-uniform
        int e = act ? (w * 64 + row) : 0;
        kreg[i] = act ? kidx_s[e] : 0;
        sreg[i] = act ? src_s[e] : 0;
        if (act) seg_prep(dst_s, w * 64, tid, ddstM[i], slotM[i], distM[i], &nsegM[i]);
    }
    __syncthreads();   // metadata visible to all waves

    for (int l = 0; l < NLAY; l++) {
        // ---------- phase A: filter-scatter (grid-stride over windows) ----------
        const bf16* TbL = Tb + (size_t)(l + 1) * NK * HC;
        #pragma unroll
        for (int i = 0; i < MAXW; i++) {
            int w = bid + i * COOPGRID;
            bool act = (w * 64 < Eact);           // block-uniform
            if (act) {
                if (i > 0) __syncthreads();       // mvT reuse (prev window's reads done)
                const bf8v* tp = (const bf8v*)(TbL + (size_t)kreg[i] * HC + c0);
                bf8v tv[4];
                #pragma unroll
                for (int g = 0; g < 4; g++) tv[g] = tp[g];
                const bf8v* yp = (const bf8v*)(ybf + (size_t)sreg[i] * HC + c0);
                bf8v yv[4];
                #pragma unroll
                for (int g = 0; g < 4; g++) yv[g] = yp[g];
                #pragma unroll
                for (int g = 0; g < 4; g++)
                    #pragma unroll
                    for (int m = 0; m < 8; m++) {
                        float v = s2f((unsigned short)tv[g][m]) *
                                  s2f((unsigned short)yv[g][m]);
                        mvT[c0 + g * 8 + m][row] = f2b(v);
                    }
                __syncthreads();
                seg_mfma(mvT, ddstM[i], slotM[i], distM[i], nsegM[i], msum, tid);
            }
        }
        grid.sync();   // all scatters (stores + atomics) visible

        // ---------- phase B: node update (blocks 0..UGRID-1) ----------
        if (bid < UGRID) {
            bf8v af[4];
            #pragma unroll
            for (int ks = 0; ks < 4; ks++)
                af[ks] = f32x8_to_b(msum + (size_t)(m0 + lc) * HC + ks * 32 + quad * 8);
            f4v acc[2] = {zero, zero};
            const bf16* c2b = cw2p + (size_t)l * 16384;
            #pragma unroll
            for (int nt = 0; nt < 2; nt++)
                #pragma unroll
                for (int ks = 0; ks < 4; ks++) {
                    bf8v b = *(const bf8v*)(c2b + (((wv * 2 + nt) * 4 + ks) * 64 + lane) * 8);
                    acc[nt] = MFMA(af[ks], b, acc[nt]);
                }
            #pragma unroll
            for (int nt = 0; nt < 2; nt++) {
                int n = wv * 32 + nt * 16 + lc;
                float bb = cb2cv[l * HC + n];
                #pragma unroll
                for (int r = 0; r < 4; r++)
                    srow[quad * 4 + r][n] = f2b(silu(acc[nt][r] + bb));
            }
            __syncthreads();
            {   // re-zero this block's msum rows for the next layer's scatter
                int zr = tid >> 4, zc = (tid & 15) * 8;
                *(f4v*)(msum + (size_t)(m0 + zr) * HC + zc) = zero;
                *(f4v*)(msum + (size_t)(m0 + zr) * HC + zc + 4) = zero;
            }
            bf8v a2[4];
            #pragma unroll
            for (int ks = 0; ks < 4; ks++)
                a2[ks] = *(const bf8v*)&srow[lc][ks * 32 + quad * 8];
            __syncthreads();
            f4v acc2[2] = {zero, zero};
            const bf16* lwb = lwp + (size_t)l * 16384;
            #pragma unroll
            for (int nt = 0; nt < 2; nt++)
                #pragma unroll
                for (int ks = 0; ks < 4; ks++) {
                    bf8v b = *(const bf8v*)(lwb + (((wv * 2 + nt) * 4 + ks) * 64 + lane) * 8);
                    acc2[nt] = MFMA(a2[ks], b, acc2[nt]);
                }
            int last = (l == NLAY - 1);
            #pragma unroll
            for (int nt = 0; nt < 2; nt++) {
                int n = wv * 32 + nt * 16 + lc;
                float bb = lbcv[l * HC + n];
                #pragma unroll
                for (int r = 0; r < 4; r++) {
                    int rw = m0 + quad * 4 + r;
                    size_t o = (size_t)rw * HC + n;
                    float nv = x[o] + acc2[nt][r] + bb;
                    if (!last) {
                        x[o] = nv;
                        xb[o] = f2b(nv);
                    } else {
                        if (isf) ((float*)out)[o] = nv;
                        else     ((bf16*)out)[o] = f2b(nv);
                    }
                    srow[quad * 4 + r][n] = f2b(nv);
                }
            }
            if (!last) {
                __syncthreads();
                bf8v a3[4];
                #pragma unroll
                for (int ks = 0; ks < 4; ks++)
                    a3[ks] = *(const bf8v*)&srow[lc][ks * 32 + quad * 8];
                f4v acc3[2] = {zero, zero};
                const bf16* c1b = cw1p + (size_t)(l + 1) * 16384;
                #pragma unroll
                for (int nt = 0; nt < 2; nt++)
                    #pragma unroll
                    for (int ks = 0; ks < 4; ks++) {
                        bf8v b = *(const bf8v*)(c1b + (((wv * 2 + nt) * 4 + ks) * 64 + lane) * 8);
                        acc3[nt] = MFMA(a3[ks], b, acc3[nt]);
                    }
                #pragma unroll
                for (int nt = 0; nt < 2; nt++) {
                    int n = wv * 32 + nt * 16 + lc;
                    #pragma unroll
                    for (int r = 0; r < 4; r++) {
                        int rw = m0 + quad * 4 + r;
                        ybf[(size_t)rw * HC + n] = f2b(acc3[nt][r]);
                    }
                }
            }
        }
        if (l < NLAY - 1) grid.sync();   // ybf/msum-zero visible for next layer
    }
}

// ---------------- fallback: filter edges (R17 path) ----------------
__global__ __launch_bounds__(256)
void filt_tab_k(int l, const int* __restrict__ rowptr,
                const int* __restrict__ kidx_s, const int* __restrict__ src_s,
                const int* __restrict__ dst_s, const bf16* __restrict__ ybf,
                const bf16* __restrict__ Tb, float* __restrict__ msum) {
    __shared__ bf16 mvT[128][72];
    __shared__ int ddst[64], slot_s[64], distinct_s[64];
    __shared__ int nseg_s;
    int i0 = blockIdx.x * 64;
    if (i0 >= rowptr[NATOMS]) return;
    int tid = threadIdx.x;
    seg_prep(dst_s, i0, tid, ddst, slot_s, distinct_s, &nseg_s);
    int row = tid & 63, c0 = (tid >> 6) * 32;
    int e = i0 + row;
    int k = kidx_s[e];
    const bf8v* tp = (const bf8v*)(Tb + ((size_t)(l + 1) * NK + k) * HC + c0);
    bf8v tv[4];
    #pragma unroll
    for (int g = 0; g < 4; g++) tv[g] = tp[g];
    const bf8v* yp = (const bf8v*)(ybf + (size_t)src_s[e] * HC + c0);
    bf8v yv[4];
    #pragma unroll
    for (int g = 0; g < 4; g++) yv[g] = yp[g];
    #pragma unroll
    for (int g = 0; g < 4; g++)
        #pragma unroll
        for (int m = 0; m < 8; m++) {
            float v = s2f((unsigned short)tv[g][m]) * s2f((unsigned short)yv[g][m]);
            mvT[c0 + g * 8 + m][row] = f2b(v);
        }
    __syncthreads();
    seg_mfma(mvT, ddst, slot_s, distinct_s, nseg_s, msum, tid);
}

// ---- fallback: node update, 16 rows/block (R17 path) ----
__global__ __launch_bounds__(256)
void upd_mfma_k(float* msum, int l,
                const bf16* __restrict__ cw2p, const float* __restrict__ cb2cv,
                const bf16* __restrict__ lwp, const float* __restrict__ lbcv,
                const bf16* __restrict__ cw1p, int do_y, int last,
                float* __restrict__ x, bf16* __restrict__ xb,
                bf16* __restrict__ ybf, void* out, const int* flagp) {
    __shared__ bf16 srow[16][136];
    int tid = threadIdx.x;
    int w = tid >> 6, lane = tid & 63, quad = lane >> 4, lc = lane & 15;
    int m0 = blockIdx.x * 16;
    bf8v af[4];
    #pragma unroll
    for (int ks = 0; ks < 4; ks++)
        af[ks] = f32x8_to_b(msum + (size_t)(m0 + lc) * HC + ks * 32 + quad * 8);
    f4v zero = {0.f, 0.f, 0.f, 0.f};
    f4v acc[2] = {zero, zero};
    const bf16* c2b = cw2p + (size_t)l * 16384;
    #pragma unroll
    for (int nt = 0; nt < 2; nt++)
        #pragma unroll
        for (int ks = 0; ks < 4; ks++) {
            bf8v b = *(const bf8v*)(c2b + (((w * 2 + nt) * 4 + ks) * 64 + lane) * 8);
            acc[nt] = MFMA(af[ks], b, acc[nt]);
        }
    #pragma unroll
    for (int nt = 0; nt < 2; nt++) {
        int n = w * 32 + nt * 16 + lc;
        float bb = cb2cv[l * HC + n];
        #pragma unroll
        for (int r = 0; r < 4; r++)
            srow[quad * 4 + r][n] = f2b(silu(acc[nt][r] + bb));
    }
    __syncthreads();
    {
        int zr = tid >> 4, zc = (tid & 15) * 8;
        *(f4v*)(msum + (size_t)(m0 + zr) * HC + zc) = zero;
        *(f4v*)(msum + (size_t)(m0 + zr) * HC + zc + 4) = zero;
    }
    bf8v a2[4];
    #pragma unroll
    for (int ks = 0; ks < 4; ks++)
        a2[ks] = *(const bf8v*)&srow[lc][ks * 32 + quad * 8];
    __syncthreads();
    f4v acc2[2] = {zero, zero};
    const bf16* lwb = lwp + (size_t)l * 16384;
    #pragma unroll
    for (int nt = 0; nt < 2; nt++)
        #pragma unroll
        for (int ks = 0; ks < 4; ks++) {
            bf8v b = *(const bf8v*)(lwb + (((w * 2 + nt) * 4 + ks) * 64 + lane) * 8);
            acc2[nt] = MFMA(a2[ks], b, acc2[nt]);
        }
    int isf = isf_of(flagp);
    #pragma unroll
    for (int nt = 0; nt < 2; nt++) {
        int n = w * 32 + nt * 16 + lc;
        float bb = lbcv[l * HC + n];
        #pragma unroll
        for (int r = 0; r < 4; r++) {
            int rw = m0 + quad * 4 + r;
            size_t o = (size_t)rw * HC + n;
            float nv = x[o] + acc2[nt][r] + bb;
            if (!last) {
                x[o] = nv;
                xb[o] = f2b(nv);
            } else {
                if (isf) ((float*)out)[o] = nv;
                else     ((bf16*)out)[o] = f2b(nv);
            }
            srow[quad * 4 + r][n] = f2b(nv);
        }
    }
    if (do_y) {
        __syncthreads();
        bf8v a3[4];
        #pragma unroll
        for (int ks = 0; ks < 4; ks++)
            a3[ks] = *(const bf8v*)&srow[lc][ks * 32 + quad * 8];
        f4v acc3[2] = {zero, zero};
        const bf16* c1b = cw1p + (size_t)(l + 1) * 16384;
        #pragma unroll
        for (int nt = 0; nt < 2; nt++)
            #pragma unroll
            for (int ks = 0; ks < 4; ks++) {
                bf8v b = *(const bf8v*)(c1b + (((w * 2 + nt) * 4 + ks) * 64 + lane) * 8);
                acc3[nt] = MFMA(a3[ks], b, acc3[nt]);
            }
        #pragma unroll
        for (int nt = 0; nt < 2; nt++) {
            int n = w * 32 + nt * 16 + lc;
            #pragma unroll
            for (int r = 0; r < 4; r++) {
                int rw = m0 + quad * 4 + r;
                ybf[(size_t)rw * HC + n] = f2b(acc3[nt][r]);
            }
        }
    }
}

// ---------------- launch ----------------
extern "C" void kernel_launch(void* const* d_in, const int* in_sizes, int n_in,
                              void* d_out, int out_size, void* d_ws, size_t ws_size,
                              hipStream_t stream) {
    const int*  z      = (const int*) d_in[0];
    const void* pos    = d_in[1];
    const int*  ei     = (const int*) d_in[3];
    const void* emb    = d_in[4];
    const void* nbremb = d_in[5];
    const void* Wp     = d_in[6];
    const void* bp     = d_in[7];
    const void* Wc     = d_in[8];
    const void* bc     = d_in[9];
    const void* means  = d_in[10];
    const void* betas  = d_in[11];
    const void* W1     = d_in[12];
    const void* b1     = d_in[13];
    const void* W2     = d_in[14];
    const void* b2     = d_in[15];
    const void* cW1    = d_in[16];
    const void* cW2    = d_in[17];
    const void* cb2    = d_in[18];
    const void* lW     = d_in[19];
    const void* lb     = d_in[20];

    char* p = (char*)d_ws;
    auto alloc = [&](size_t bytes) { char* r = p; p += (bytes + 255) / 256 * 256; return r; };
    int*   flag    = (int*)  alloc(256);
    int*   counts  = (int*)  alloc((size_t)NATOMS * 4);
    float* msum    = (float*)alloc((size_t)NATOMS * HC * 4);
    float* msg     = (float*)alloc((size_t)NATOMS * HC * 4);
    int*   kidx_s  = (int*)  alloc((size_t)NEDGES * 4);
    int*   src_s   = (int*)  alloc((size_t)NEDGES * 4);
    int*   dst_s   = (int*)  alloc((size_t)NEDGES * 4);
    char*  zend    = p;
    int*   rowptr  = (int*)  alloc((size_t)(NATOMS + 1) * 4);
    int*   cursor  = (int*)  alloc((size_t)NATOMS * 4);
    float* d_raw   = (float*)alloc((size_t)NEDGES * 4);
    float* x       = (float*)alloc((size_t)NATOMS * HC * 4);
    bf16*  xb      = (bf16*) alloc((size_t)NATOMS * HC * 2);
    bf16*  ybf     = (bf16*) alloc((size_t)NATOMS * HC * 2);
    bf16*  Tb      = (bf16*) alloc((size_t)(NLAY + 1) * NK * HC * 2);  // 14.7 MB
    bf16*  wpp     = (bf16*) alloc((size_t)8192 * 2);
    bf16*  wcp     = (bf16*) alloc((size_t)32768 * 2);
    bf16*  w1p     = (bf16*) alloc((size_t)NLAY * 8192 * 2);
    bf16*  w2p     = (bf16*) alloc((size_t)NLAY * 16384 * 2);
    bf16*  cw1p    = (bf16*) alloc((size_t)NLAY * 16384 * 2);
    bf16*  cw2p    = (bf16*) alloc((size_t)NLAY * 16384 * 2);
    bf16*  lwp     = (bf16*) alloc((size_t)NLAY * 16384 * 2);
    bf16*  nbrembbf= (bf16*) alloc((size_t)MAXZ_ * HC * 2);
    float* bpcv    = (float*)alloc((size_t)HC * 4);
    float* bccv    = (float*)alloc((size_t)HC * 4);
    float* b1cv    = (float*)alloc((size_t)NLAY * HC * 4);
    float* b2cv    = (float*)alloc((size_t)NLAY * HC * 4);
    float* cb2cv   = (float*)alloc((size_t)NLAY * HC * 4);
    float* lbcv    = (float*)alloc((size_t)NLAY * HC * 4);
    float* meanscv = (float*)alloc((size_t)RBF * 4);
    float* betascv = (float*)alloc((size_t)RBF * 4);

    hipMemsetAsync(flag, 0, (size_t)(zend - (char*)flag), stream);
    probe_k<<<(NATOMS * 3 + 255) / 256, 256, 0, stream>>>(pos, flag);

    setup1_k<<<EG + 300, 256, 0, stream>>>(ei, pos, flag, counts, d_raw,
                                           Wp, Wc, W1, W2, cW1, cW2, lW, means, betas,
                                           bp, bc, b1, b2, cb2, lb, nbremb,
                                           wpp, wcp, w1p, w2p, cw1p, cw2p, lwp,
                                           meanscv, betascv, bpcv, bccv, b1cv, b2cv,
                                           cb2cv, lbcv, nbrembbf);
    scan_k<<<1, 1024, 0, stream>>>(counts, rowptr, cursor);
    setup2_k<<<EG + TBGRID, 256, 0, stream>>>(ei, d_raw, cursor, kidx_s, src_s, dst_s,
                                              wpp, bpcv, w1p, b1cv, w2p, b2cv,
                                              meanscv, betascv, Tb);

    nbr_tab_k<<<EGRID, 256, 0, stream>>>(rowptr, kidx_s, src_s, dst_s, z, nbrembbf,
                                         Tb, msg);
    combine_k<<<YGRID, 256, 0, stream>>>(z, emb, msg, wcp, bccv, cw1p, flag, x, xb, ybf);

    // cooperative fused layer loop; fall back to 12-dispatch path on rejection
    bool coop_ok = false;
    {
        void* args[] = { (void*)&rowptr, (void*)&kidx_s, (void*)&src_s, (void*)&dst_s,
                         (void*)&Tb, (void*)&msum, (void*)&cw2p, (void*)&cb2cv,
                         (void*)&lwp, (void*)&lbcv, (void*)&cw1p, (void*)&x,
                         (void*)&xb, (void*)&ybf, (void*)&d_out, (void*)&flag };
        hipError_t rc = hipLaunchCooperativeKernel((const void*)layers_k,
                                                   dim3(COOPGRID), dim3(256),
                                                   args, 0, stream);
        coop_ok = (rc == hipSuccess);
        if (!coop_ok) (void)hipGetLastError();   // clear sticky error
    }
    if (!coop_ok) {
        for (int l = 0; l < NLAY; l++) {
            filt_tab_k<<<EGRID, 256, 0, stream>>>(l, rowptr, kidx_s, src_s, dst_s, ybf,
                                                  Tb, msum);
            int lastl = (l == NLAY - 1) ? 1 : 0;
            upd_mfma_k<<<UGRID, 256, 0, stream>>>(msum, l, cw2p, cb2cv, lwp, lbcv,
                                                  cw1p, lastl ? 0 : 1, lastl,
                                                  x, xb, ybf, d_out, flag);
        }
    }
}

// Round 7
// 337.533 us; speedup vs baseline: 5.3055x; 5.3055x over previous
//
#include <hip/hip_runtime.h>
#include <hip/hip_bf16.h>

// TorchMD_GN_Ext R19: revert R18's cooperative fusion (grid.sync measured ~130-145us
// per sync on MI355X -- layers_k counters: 1614us, MfmaUtil 0.19%, VALUBusy 1.2%).
// Base = R17 (best known-good, 333.9us). New in R19:
//  - host-side dtype detection from in_sizes (bytes semantics confirmed via
//    in_sizes[0]==NATOMS*4 for int32 z): probe_k dispatch removed when detectable
//    (f32 -> 4-byte memset 0x7F into flag; bf16 -> flag stays 0 from big memset);
//    unknown sizes -> probe path unchanged (zero-risk fallback)
//  - isf passed as literal kernel arg to setup1/combine/upd (removes the dependent
//    flag load at kernel head; arg==-1 -> read flag as before)
//  18 kernel dispatches + 1-2 memsets (detected path).

#define NATOMS 10000
#define NEDGES 320000
#define HC 128
#define RBF 50
#define NLAY 6
#define MAXZ_ 100
#define NK 8192
#define EG 1250                     // (NEDGES+255)/256
#define TBGRID (7 * (NK / 64))      // 896
#define EGRID (NEDGES / 64)         // 5000 worst case; blocks early-exit past Eact
#define YGRID ((NATOMS + 63) / 64)  // 157
#define UGRID (NATOMS / 16)         // 625 (NATOMS % 16 == 0)

typedef __hip_bfloat16 bf16;
typedef __attribute__((ext_vector_type(8))) short bf8v;
typedef __attribute__((ext_vector_type(4))) float f4v;
typedef __attribute__((ext_vector_type(4))) int i4v;

__device__ __forceinline__ float b2f(bf16 v) { return __bfloat162float(v); }
__device__ __forceinline__ bf16  f2b(float v) { return __float2bfloat16(v); }
__device__ __forceinline__ short f2s(float v) { bf16 h = f2b(v); return *(short*)&h; }
__device__ __forceinline__ float s2f(unsigned short s) {
    return __int_as_float(((int)s) << 16);
}
__device__ __forceinline__ float silu(float v) {
    return v * __builtin_amdgcn_rcpf(1.0f + __expf(-v));
}
__device__ __forceinline__ int isf_of(const int* flagp) {
    return (__int_as_float(flagp[0]) > 1.0e4f) ? 1 : 0;
}

template<int ISF>
__device__ __forceinline__ float LD(const void* p, size_t i) {
    if (ISF) return ((const float*)p)[i];
    return b2f(((const bf16*)p)[i]);
}

// 8 consecutive f32 -> bf8v via two dwordx4 loads (same rounding as scalar path)
__device__ __forceinline__ bf8v f32x8_to_b(const float* p) {
    f4v v0 = *(const f4v*)p;
    f4v v1 = *(const f4v*)(p + 4);
    bf8v r;
    r[0] = f2s(v0[0]); r[1] = f2s(v0[1]); r[2] = f2s(v0[2]); r[3] = f2s(v0[3]);
    r[4] = f2s(v1[0]); r[5] = f2s(v1[1]); r[6] = f2s(v1[2]); r[7] = f2s(v1[3]);
    return r;
}
template<int ISF>
__device__ __forceinline__ bf8v LD8(const void* p, size_t i) {
    if (ISF) return f32x8_to_b((const float*)p + i);
    return *(const bf8v*)((const bf16*)p + i);
}

__device__ __forceinline__ int clampN(int v) {
    return v < 0 ? 0 : (v >= NATOMS ? NATOMS - 1 : v);
}

// edge distance (computed once, in histd; cached to d_raw for permgeom)
template<int ISF>
__device__ __forceinline__ float edge_d(const int* __restrict__ ei,
                                        const void* __restrict__ pos, int e,
                                        int* sOut, int* tOut) {
    int s = clampN(ei[e]);
    int t = clampN(ei[NEDGES + e]);
    *sOut = s; *tOut = t;
    float dx = LD<ISF>(pos, (size_t)s * 3 + 0) - LD<ISF>(pos, (size_t)t * 3 + 0);
    float dy = LD<ISF>(pos, (size_t)s * 3 + 1) - LD<ISF>(pos, (size_t)t * 3 + 1);
    float dz = LD<ISF>(pos, (size_t)s * 3 + 2) - LD<ISF>(pos, (size_t)t * 3 + 2);
    float d = sqrtf(dx * dx + dy * dy + dz * dz + 1e-12f);
    if (d != d) d = 1e30f;
    return d;
}

// ---------------- dtype probe (fallback only, when in_sizes semantics unknown) ----
__global__ void probe_k(const void* pos, int* flag) {
    int i = blockIdx.x * 256 + threadIdx.x;
    float v = 0.0f;
    if (i < NATOMS * 3) {
        v = fabsf(b2f(((const bf16*)pos)[i]));
        if (v != v) v = 1e30f;
    }
    #pragma unroll
    for (int off = 32; off > 0; off >>= 1)
        v = fmaxf(v, __shfl_xor(v, off, 64));
    if ((threadIdx.x & 63) == 0) atomicMax(flag, __float_as_int(v));
}

// ------- histogram of ACTIVE (d<5) edges + d cache -------
template<int ISF>
__device__ __forceinline__ void histd_body(int b, int tid, const int* __restrict__ ei,
                                           const void* __restrict__ pos,
                                           int* __restrict__ counts,
                                           float* __restrict__ d_raw) {
    int e = b * 256 + tid;
    if (e >= NEDGES) return;
    int s, t;
    float d = edge_d<ISF>(ei, pos, e, &s, &t);
    d_raw[e] = d;            // cache for permgeom (bit-identical d)
    if (d < 5.0f) atomicAdd(&counts[t], 1);
}

// ---------------- mega pack/convert ----------------
template<int ISF>
__device__ void packB_at(int t, const void* src, int K, int ksteps, size_t perLsrc,
                         size_t perLdst, int L, bf16* dst) {
    if (t >= L * 8 * ksteps * 64) return;
    int lane = t & 63;
    int t2 = t >> 6;
    int ks = t2 % ksteps;
    int t3 = t2 / ksteps;
    int nt = t3 & 7;
    int l  = t3 >> 3;
    int quad = lane >> 4, lc = lane & 15;
    int col = nt * 16 + lc;
    for (int j = 0; j < 8; j++) {
        int k = ks * 32 + quad * 8 + j;
        float v = (k < K) ? LD<ISF>(src, (size_t)l * perLsrc + (size_t)k * 128 + col) : 0.0f;
        dst[(size_t)l * perLdst + ((size_t)((nt * ksteps + ks) * 64 + lane)) * 8 + j] = f2b(v);
    }
}
template<int ISF>
__device__ void packB24_at(int t, const void* w2, const void* cw1, const void* cw2,
                           const void* lw, bf16* w2p, bf16* cw1p, bf16* cw2p, bf16* lwp) {
    if (t >= 24 * 8 * 4 * 64) return;
    int lane = t & 63;
    int t2 = t >> 6;
    int ks = t2 & 3;
    int t3 = t2 >> 2;
    int nt = t3 & 7;
    int m  = t3 >> 3;
    int which = m / NLAY, li = m % NLAY;
    const void* src = which == 0 ? w2 : which == 1 ? cw1 : which == 2 ? cw2 : lw;
    bf16* dst = which == 0 ? w2p : which == 1 ? cw1p : which == 2 ? cw2p : lwp;
    int quad = lane >> 4, lc = lane & 15;
    int col = nt * 16 + lc;
    #pragma unroll
    for (int j = 0; j < 8; j++) {
        int k = ks * 32 + quad * 8 + j;
        float v = LD<ISF>(src, (size_t)li * 16384 + (size_t)k * 128 + col);
        dst[(size_t)li * 16384 + ((size_t)((nt * 4 + ks) * 64 + lane)) * 8 + j] = f2b(v);
    }
}
template<int ISF>
__device__ void cvts_at(int i, const void* means, const void* betas, const void* bp,
                        const void* bc, const void* b1, const void* b2,
                        const void* cb2, const void* lb,
                        float* meanscv, float* betascv, float* bpcv, float* bccv,
                        float* b1cv, float* b2cv, float* cb2cv, float* lbcv) {
    if      (i < 50)   meanscv[i]        = LD<ISF>(means, i);
    else if (i < 100)  betascv[i - 50]   = LD<ISF>(betas, i - 50);
    else if (i < 228)  bpcv[i - 100]     = LD<ISF>(bp, i - 100);
    else if (i < 356)  bccv[i - 228]     = LD<ISF>(bc, i - 228);
    else if (i < 1124) b1cv[i - 356]     = LD<ISF>(b1, i - 356);
    else if (i < 1892) b2cv[i - 1124]    = LD<ISF>(b2, i - 1124);
    else if (i < 2660) cb2cv[i - 1892]   = LD<ISF>(cb2, i - 1892);
    else if (i < 3428) lbcv[i - 2660]    = LD<ISF>(lb, i - 2660);
}
template<int ISF>
__device__ void packall_body(int b, int tid, const void* Wp, const void* Wc, const void* W1,
                             const void* W2, const void* cW1, const void* cW2,
                             const void* lW, const void* means, const void* betas,
                             const void* bp, const void* bc, const void* b1,
                             const void* b2, const void* cb2, const void* lb,
                             const void* nbremb,
                             bf16* wpp, bf16* wcp, bf16* w1p, bf16* w2p, bf16* cw1p,
                             bf16* cw2p, bf16* lwp, float* meanscv, float* betascv,
                             float* bpcv, float* bccv, float* b1cv, float* b2cv,
                             float* cb2cv, float* lbcv, bf16* nbrembbf) {
    if (b < 4)        packB_at<ISF>(b * 256 + tid, Wp, RBF, 2, 6400, 8192, 1, wpp);
    else if (b < 20)  packB_at<ISF>((b - 4) * 256 + tid, Wc, 256, 8, 32768, 32768, 1, wcp);
    else if (b < 44)  packB_at<ISF>((b - 20) * 256 + tid, W1, RBF, 2, 6400, 8192, NLAY, w1p);
    else if (b < 236) packB24_at<ISF>((b - 44) * 256 + tid, W2, cW1, cW2, lW,
                                      w2p, cw1p, cw2p, lwp);
    else if (b < 250) cvts_at<ISF>((b - 236) * 256 + tid, means, betas, bp, bc, b1, b2,
                                   cb2, lb, meanscv, betascv, bpcv, bccv,
                                   b1cv, b2cv, cb2cv, lbcv);
    else {
        int i = (b - 250) * 256 + tid;
        if (i < MAXZ_ * HC) nbrembbf[i] = f2b(LD<ISF>(nbremb, i));
    }
}

// -------- setup1: histd (blocks 0..1249) + packall (blocks 1250..1549) --------
__global__ __launch_bounds__(256)
void setup1_k(const int* ei, const void* pos, const int* flagp, int isf_arg,
              int* counts, float* d_raw,
              const void* Wp, const void* Wc, const void* W1,
              const void* W2, const void* cW1, const void* cW2,
              const void* lW, const void* means, const void* betas,
              const void* bp, const void* bc, const void* b1,
              const void* b2, const void* cb2, const void* lb,
              const void* nbremb,
              bf16* wpp, bf16* wcp, bf16* w1p, bf16* w2p, bf16* cw1p,
              bf16* cw2p, bf16* lwp, float* meanscv, float* betascv,
              float* bpcv, float* bccv, float* b1cv, float* b2cv,
              float* cb2cv, float* lbcv, bf16* nbrembbf) {
    int b = blockIdx.x, tid = threadIdx.x;
    int isf = (isf_arg >= 0) ? isf_arg : isf_of(flagp);
    if (b < EG) {
        if (isf) histd_body<1>(b, tid, ei, pos, counts, d_raw);
        else     histd_body<0>(b, tid, ei, pos, counts, d_raw);
    } else {
        b -= EG;
        if (isf) packall_body<1>(b, tid, Wp, Wc, W1, W2, cW1, cW2, lW, means, betas,
                                 bp, bc, b1, b2, cb2, lb, nbremb, wpp, wcp,
                                 w1p, w2p, cw1p, cw2p, lwp, meanscv, betascv,
                                 bpcv, bccv, b1cv, b2cv, cb2cv, lbcv, nbrembbf);
        else     packall_body<0>(b, tid, Wp, Wc, W1, W2, cW1, cW2, lW, means, betas,
                                 bp, bc, b1, b2, cb2, lb, nbremb, wpp, wcp,
                                 w1p, w2p, cw1p, cw2p, lwp, meanscv, betascv,
                                 bpcv, bccv, b1cv, b2cv, cb2cv, lbcv, nbrembbf);
    }
}

// ---------------- scan (one-pass: 10 elems/thread) ----------------
__global__ void scan_k(const int* __restrict__ counts, int* __restrict__ rowptr,
                       int* __restrict__ cursor) {
    __shared__ int wsum[16];
    int tid = threadIdx.x, lane = tid & 63, w = tid >> 6;
    int base = tid * 10;
    int v[10];
    int s = 0;
    #pragma unroll
    for (int j = 0; j < 10; j++) {
        int i = base + j;
        int c = (i < NATOMS) ? counts[i] : 0;
        v[j] = c; s += c;
    }
    int si = s;
    #pragma unroll
    for (int off = 1; off < 64; off <<= 1) {
        int t = __shfl_up(si, off, 64);
        if (lane >= off) si += t;
    }
    if (lane == 63) wsum[w] = si;
    __syncthreads();
    if (w == 0 && lane < 16) {
        int t = wsum[lane];
        int s2 = t;
        #pragma unroll
        for (int off = 1; off < 16; off <<= 1) {
            int u = __shfl_up(s2, off, 64);
            if (lane >= off) s2 += u;
        }
        wsum[lane] = s2 - t;   // exclusive wave prefix
    }
    __syncthreads();
    int run = wsum[w] + si - s;   // exclusive prefix of this thread's chunk
    #pragma unroll
    for (int j = 0; j < 10; j++) {
        int i = base + j;
        if (i < NATOMS) {
            cursor[i] = run;
            run += v[j];
            rowptr[i + 1] = run;
        }
    }
    if (tid == 0) rowptr[0] = 0;
}

// ---------------- MFMA helpers ----------------
#define MFMA(a, b, c) __builtin_amdgcn_mfma_f32_16x16x32_bf16((a), (b), (c), 0, 0, 0)

// ---------- permgeom body (blocks 0..1249 of setup2) ----------
__device__ __forceinline__ void permgeom_body(int b, int tid, const int* __restrict__ ei,
                                              const float* __restrict__ d_raw,
                                              int* __restrict__ cursor,
                                              int* __restrict__ kidx_s,
                                              int* __restrict__ src_s,
                                              int* __restrict__ dst_s) {
    int e = b * 256 + tid;
    if (e >= NEDGES) return;
    float d = d_raw[e];
    if (d >= 5.0f) return;                  // dead edge: exactly 0 contribution
    int s = clampN(ei[e]);
    int t = clampN(ei[NEDGES + e]);
    int p = atomicAdd(&cursor[t], 1);
    float ed = __expf(-d);
    // identical formula to the old per-kernel k computation (bit-identical k)
    float pos = fminf(fmaxf(ed * (float)(NK - 1) + 0.5f, 0.0f), (float)(NK - 1));
    kidx_s[p] = (int)pos;
    src_s[p] = s;
    dst_s[p] = t;
}

// ---------- tabbuild body (blocks 1250.. of setup2) ----------
__device__ __forceinline__ void tabbuild_body(int bb, int tid,
                const bf16* __restrict__ wpp, const float* __restrict__ bpcv,
                const bf16* __restrict__ w1p, const float* __restrict__ b1cv,
                const bf16* __restrict__ w2p, const float* __restrict__ b2cv,
                const float* __restrict__ meanscv, const float* __restrict__ betascv,
                bf16* __restrict__ Tb) {
    __shared__ bf16 hid[64][136];
    __shared__ float csh[64], edsh[64];
    int f = bb >> 7, kb = bb & 127;
    int base = kb * 64;
    int wave = tid >> 6, lane = tid & 63, quad = lane >> 4, lc = lane & 15;
    if (tid < 64) {
        float ed = (float)(base + tid) * (1.0f / (NK - 1));
        float d = -logf(fmaxf(ed, 1e-30f));
        float C = (d < 5.0f) ? 0.5f * (__cosf(d * 0.6283185307f) + 1.0f) : 0.0f;
        csh[tid] = C; edsh[tid] = ed;
    }
    __syncthreads();
    float edi = edsh[wave * 16 + lc], Ci = csh[wave * 16 + lc];
    bf8v af[2];
    #pragma unroll
    for (int ks = 0; ks < 2; ks++) {
        #pragma unroll
        for (int j = 0; j < 8; j++) {
            int r = ks * 32 + quad * 8 + j;
            float v = 0.0f;
            if (r < RBF) { float u = edi - meanscv[r]; v = Ci * __expf(-betascv[r] * u * u); }
            af[ks][j] = f2s(v);
        }
    }
    f4v zero = {0.f, 0.f, 0.f, 0.f};
    f4v acc[8];
    #pragma unroll
    for (int nt = 0; nt < 8; nt++) acc[nt] = zero;
    const bf16* w1b = (f == 0) ? wpp : w1p + (size_t)(f - 1) * 8192;
    #pragma unroll
    for (int nt = 0; nt < 8; nt++)
        #pragma unroll
        for (int ks = 0; ks < 2; ks++) {
            bf8v b = *(const bf8v*)(w1b + ((nt * 2 + ks) * 64 + lane) * 8);
            acc[nt] = MFMA(af[ks], b, acc[nt]);
        }
    if (f == 0) {
        #pragma unroll
        for (int nt = 0; nt < 8; nt++) {
            int n = nt * 16 + lc;
            float bb2 = bpcv[n];
            #pragma unroll
            for (int r = 0; r < 4; r++) {
                int row = wave * 16 + quad * 4 + r;
                Tb[(size_t)(base + row) * HC + n] = f2b((acc[nt][r] + bb2) * csh[row]);
            }
        }
        return;
    }
    int l = f - 1;
    #pragma unroll
    for (int nt = 0; nt < 8; nt++) {
        int n = nt * 16 + lc;
        float bb2 = b1cv[l * HC + n];
        #pragma unroll
        for (int r = 0; r < 4; r++)
            hid[wave * 16 + quad * 4 + r][n] = f2b(silu(acc[nt][r] + bb2));
    }
    __syncthreads();
    bf8v a2[4];
    #pragma unroll
    for (int ks = 0; ks < 4; ks++)
        a2[ks] = *(const bf8v*)&hid[wave * 16 + lc][ks * 32 + quad * 8];
    f4v acc2[8];
    #pragma unroll
    for (int nt = 0; nt < 8; nt++) acc2[nt] = zero;
    const bf16* w2b = w2p + (size_t)l * 16384;
    #pragma unroll
    for (int nt = 0; nt < 8; nt++)
        #pragma unroll
        for (int ks = 0; ks < 4; ks++) {
            bf8v b = *(const bf8v*)(w2b + ((nt * 4 + ks) * 64 + lane) * 8);
            acc2[nt] = MFMA(a2[ks], b, acc2[nt]);
        }
    #pragma unroll
    for (int nt = 0; nt < 8; nt++) {
        int n = nt * 16 + lc;
        float bb2 = b2cv[l * HC + n];
        #pragma unroll
        for (int r = 0; r < 4; r++) {
            int row = wave * 16 + quad * 4 + r;
            Tb[((size_t)f * NK + base + row) * HC + n] = f2b((acc2[nt][r] + bb2) * csh[row]);
        }
    }
}

// -------- setup2: permgeom (blocks 0..1249) + tabbuild (blocks 1250..2145) --------
__global__ __launch_bounds__(256)
void setup2_k(const int* ei, const float* d_raw, int* cursor,
              int* kidx_s, int* src_s, int* dst_s,
              const bf16* wpp, const float* bpcv,
              const bf16* w1p, const float* b1cv,
              const bf16* w2p, const float* b2cv,
              const float* meanscv, const float* betascv, bf16* Tb) {
    int b = blockIdx.x, tid = threadIdx.x;
    if (b < EG) permgeom_body(b, tid, ei, d_raw, cursor, kidx_s, src_s, dst_s);
    else        tabbuild_body(b - EG, tid, wpp, bpcv, w1p, b1cv, w2p, b2cv,
                              meanscv, betascv, Tb);
}

// ---------------- segment helpers ----------------
__device__ __forceinline__ void seg_prep(const int* __restrict__ dst_s, int i0, int tid,
                                         int* ddst, int* slot_s, int* distinct_s,
                                         int* nseg_s) {
    if (tid < 64) {
        int d = dst_s[i0 + tid];
        ddst[tid] = d;
        int dprev = __shfl_up(d, 1, 64);
        int flag = (tid == 0 || d != dprev) ? 1 : 0;
        int s = flag;
        #pragma unroll
        for (int off = 1; off < 64; off <<= 1) {
            int t = __shfl_up(s, off, 64);
            if (tid >= off) s += t;
        }
        slot_s[tid] = s - 1;
        if (flag) distinct_s[s - 1] = d;
        if (tid == 63) *nseg_s = s;
    }
}

__device__ __forceinline__ void seg_mfma(const bf16 (*mvT)[72], const int* ddst,
                                         const int* slot_s, const int* distinct_s,
                                         int nseg, float* __restrict__ out, int tid) {
    int wave = tid >> 6, lane = tid & 63, quad = lane >> 4, lc = lane & 15;
    if (nseg <= 16) {
        bf8v sa[2];
        #pragma unroll
        for (int ks = 0; ks < 2; ks++) {
            int k0 = ks * 32 + quad * 8;
            i4v s0 = *(const i4v*)&slot_s[k0];
            i4v s1 = *(const i4v*)&slot_s[k0 + 4];
            #pragma unroll
            for (int j = 0; j < 4; j++) {
                sa[ks][j]     = (s0[j] == lc) ? (short)0x3F80 : (short)0;
                sa[ks][j + 4] = (s1[j] == lc) ? (short)0x3F80 : (short)0;
            }
        }
        f4v z4 = {0.f, 0.f, 0.f, 0.f};
        f4v sacc[2] = {z4, z4};
        #pragma unroll
        for (int nt = 0; nt < 2; nt++)
            #pragma unroll
            for (int ks = 0; ks < 2; ks++) {
                bf8v b = *(const bf8v*)&mvT[wave * 32 + nt * 16 + lc][ks * 32 + quad * 8];
                sacc[nt] = MFMA(sa[ks], b, sacc[nt]);
            }
        #pragma unroll
        for (int nt = 0; nt < 2; nt++)
            #pragma unroll
            for (int r = 0; r < 4; r++) {
                int sl = quad * 4 + r;
                if (sl < nseg) {
                    int atom = distinct_s[sl];
                    int n = wave * 32 + nt * 16 + lc;
                    float v = sacc[nt][r];
                    if (sl == 0 || sl == nseg - 1)
                        atomicAdd(&out[(size_t)atom * HC + n], v);
                    else
                        out[(size_t)atom * HC + n] = v;
                }
            }
    } else {
        int col = tid & 127;
        int base = (tid >> 7) * 32;
        int cur = ddst[base];
        float s = 0.0f;
        bool first = true;
        for (int e = base; e < base + 32; e++) {
            int dn = ddst[e];
            if (dn != cur) {
                if (first) atomicAdd(&out[(size_t)cur * HC + col], s);
                else out[(size_t)cur * HC + col] = s;
                first = false; cur = dn; s = 0.0f;
            }
            s += b2f(mvT[col][e]);
        }
        atomicAdd(&out[(size_t)cur * HC + col], s);
    }
}

// ---------------- neighbor edges ----------------
__global__ __launch_bounds__(256)
void nbr_tab_k(const int* __restrict__ rowptr,
               const int* __restrict__ kidx_s, const int* __restrict__ src_s,
               const int* __restrict__ dst_s, const int* __restrict__ z,
               const bf16* __restrict__ nbrembbf, const bf16* __restrict__ Tb,
               float* __restrict__ msg) {
    __shared__ bf16 mvT[128][72];
    __shared__ int ddst[64], slot_s[64], distinct_s[64];
    __shared__ int nseg_s;
    int i0 = blockIdx.x * 64;
    if (i0 >= rowptr[NATOMS]) return;
    int tid = threadIdx.x;
    seg_prep(dst_s, i0, tid, ddst, slot_s, distinct_s, &nseg_s);
    int row = tid & 63, c0 = (tid >> 6) * 32;
    int e = i0 + row;
    int s = src_s[e];
    float msk = (s != dst_s[e]) ? 1.0f : 0.0f;
    int k = kidx_s[e];
    const bf8v* tp = (const bf8v*)(Tb + (size_t)k * HC + c0);
    bf8v tv[4];
    #pragma unroll
    for (int g = 0; g < 4; g++) tv[g] = tp[g];
    int zz = z[s]; zz = zz < 0 ? 0 : (zz >= MAXZ_ ? MAXZ_ - 1 : zz);
    const bf8v* ep = (const bf8v*)(nbrembbf + (size_t)zz * HC + c0);
    bf8v ev[4];
    #pragma unroll
    for (int g = 0; g < 4; g++) ev[g] = ep[g];
    #pragma unroll
    for (int g = 0; g < 4; g++)
        #pragma unroll
        for (int m = 0; m < 8; m++) {
            float v = s2f((unsigned short)tv[g][m]) * msk *
                      s2f((unsigned short)ev[g][m]);
            mvT[c0 + g * 8 + m][row] = f2b(v);
        }
    __syncthreads();
    seg_mfma(mvT, ddst, slot_s, distinct_s, nseg_s, msg, tid);
}

// ---------------- combine (prep fused) ----------------
template<int ISF>
__device__ void combine_body(const int* __restrict__ z, const void* __restrict__ emb,
                             const float* __restrict__ msg, const bf16* __restrict__ wcp,
                             const float* __restrict__ bccv, const bf16* __restrict__ cw1b,
                             float* __restrict__ x, bf16* __restrict__ xb,
                             bf16* __restrict__ ybf) {
    __shared__ bf16 srow[64][136];
    int tid = threadIdx.x;
    int wave = tid >> 6, lane = tid & 63, quad = lane >> 4, lc = lane & 15;
    int m0 = blockIdx.x * 64;
    int arow = m0 + wave * 16 + lc;
    int rowc = arow < NATOMS ? arow : NATOMS - 1;
    int zz = z[rowc]; zz = zz < 0 ? 0 : (zz >= MAXZ_ ? MAXZ_ - 1 : zz);
    bf8v af[8];
    #pragma unroll
    for (int ks = 0; ks < 4; ks++)
        af[ks] = LD8<ISF>(emb, (size_t)zz * HC + ks * 32 + quad * 8);
    #pragma unroll
    for (int ks = 4; ks < 8; ks++)
        af[ks] = f32x8_to_b(msg + (size_t)rowc * HC + (ks - 4) * 32 + quad * 8);
    f4v zero = {0.f, 0.f, 0.f, 0.f};
    f4v acc[8];
    #pragma unroll
    for (int nt = 0; nt < 8; nt++) acc[nt] = zero;
    #pragma unroll
    for (int nt = 0; nt < 8; nt++)
        #pragma unroll
        for (int ks = 0; ks < 8; ks++) {
            bf8v b = *(const bf8v*)(wcp + ((nt * 8 + ks) * 64 + lane) * 8);
            acc[nt] = MFMA(af[ks], b, acc[nt]);
        }
    #pragma unroll
    for (int nt = 0; nt < 8; nt++) {
        int n = nt * 16 + lc;
        float bb = bccv[n];
        #pragma unroll
        for (int r = 0; r < 4; r++) {
            int row = m0 + wave * 16 + quad * 4 + r;
            float v = acc[nt][r] + bb;
            bf16 vb = f2b(v);
            srow[wave * 16 + quad * 4 + r][n] = vb;
            if (row < NATOMS) {
                x[(size_t)row * HC + n] = v;
                xb[(size_t)row * HC + n] = vb;
            }
        }
    }
    __syncthreads();
    bf8v a3[4];
    #pragma unroll
    for (int ks = 0; ks < 4; ks++)
        a3[ks] = *(const bf8v*)&srow[wave * 16 + lc][ks * 32 + quad * 8];
    f4v acc3[8];
    #pragma unroll
    for (int nt = 0; nt < 8; nt++) acc3[nt] = zero;
    #pragma unroll
    for (int nt = 0; nt < 8; nt++)
        #pragma unroll
        for (int ks = 0; ks < 4; ks++) {
            bf8v b = *(const bf8v*)(cw1b + ((nt * 4 + ks) * 64 + lane) * 8);
            acc3[nt] = MFMA(a3[ks], b, acc3[nt]);
        }
    #pragma unroll
    for (int nt = 0; nt < 8; nt++) {
        int n = nt * 16 + lc;
        #pragma unroll
        for (int r = 0; r < 4; r++) {
            int row = m0 + wave * 16 + quad * 4 + r;
            if (row < NATOMS) ybf[(size_t)row * HC + n] = f2b(acc3[nt][r]);
        }
    }
}
__global__ __launch_bounds__(256)
void combine_k(const int* z, const void* emb, const float* msg, const bf16* wcp,
               const float* bccv, const bf16* cw1b, const int* flagp, int isf_arg,
               float* x, bf16* xb, bf16* ybf) {
    int isf = (isf_arg >= 0) ? isf_arg : isf_of(flagp);
    if (isf) combine_body<1>(z, emb, msg, wcp, bccv, cw1b, x, xb, ybf);
    else     combine_body<0>(z, emb, msg, wcp, bccv, cw1b, x, xb, ybf);
}

// ---------------- filter edges ----------------
__global__ __launch_bounds__(256)
void filt_tab_k(int l, const int* __restrict__ rowptr,
                const int* __restrict__ kidx_s, const int* __restrict__ src_s,
                const int* __restrict__ dst_s, const bf16* __restrict__ ybf,
                const bf16* __restrict__ Tb, float* __restrict__ msum) {
    __shared__ bf16 mvT[128][72];
    __shared__ int ddst[64], slot_s[64], distinct_s[64];
    __shared__ int nseg_s;
    int i0 = blockIdx.x * 64;
    if (i0 >= rowptr[NATOMS]) return;
    int tid = threadIdx.x;
    seg_prep(dst_s, i0, tid, ddst, slot_s, distinct_s, &nseg_s);
    int row = tid & 63, c0 = (tid >> 6) * 32;
    int e = i0 + row;
    int k = kidx_s[e];
    const bf8v* tp = (const bf8v*)(Tb + ((size_t)(l + 1) * NK + k) * HC + c0);
    bf8v tv[4];
    #pragma unroll
    for (int g = 0; g < 4; g++) tv[g] = tp[g];
    const bf8v* yp = (const bf8v*)(ybf + (size_t)src_s[e] * HC + c0);
    bf8v yv[4];
    #pragma unroll
    for (int g = 0; g < 4; g++) yv[g] = yp[g];
    #pragma unroll
    for (int g = 0; g < 4; g++)
        #pragma unroll
        for (int m = 0; m < 8; m++) {
            float v = s2f((unsigned short)tv[g][m]) * s2f((unsigned short)yv[g][m]);
            mvT[c0 + g * 8 + m][row] = f2b(v);
        }
    __syncthreads();
    seg_mfma(mvT, ddst, slot_s, distinct_s, nseg_s, msum, tid);
}

// ---- node update, 16 rows/block (625 blocks for TLP) ----
__global__ __launch_bounds__(256)
void upd_mfma_k(float* msum, int l,
                const bf16* __restrict__ cw2p, const float* __restrict__ cb2cv,
                const bf16* __restrict__ lwp, const float* __restrict__ lbcv,
                const bf16* __restrict__ cw1p, int do_y, int last,
                float* __restrict__ x, bf16* __restrict__ xb,
                bf16* __restrict__ ybf, void* out, const int* flagp, int isf_arg) {
    __shared__ bf16 srow[16][136];
    int tid = threadIdx.x;
    int w = tid >> 6, lane = tid & 63, quad = lane >> 4, lc = lane & 15;
    int m0 = blockIdx.x * 16;     // NATOMS % 16 == 0 -> no row guards
    bf8v af[4];
    #pragma unroll
    for (int ks = 0; ks < 4; ks++)
        af[ks] = f32x8_to_b(msum + (size_t)(m0 + lc) * HC + ks * 32 + quad * 8);
    f4v zero = {0.f, 0.f, 0.f, 0.f};
    f4v acc[2] = {zero, zero};
    const bf16* c2b = cw2p + (size_t)l * 16384;
    #pragma unroll
    for (int nt = 0; nt < 2; nt++)
        #pragma unroll
        for (int ks = 0; ks < 4; ks++) {
            bf8v b = *(const bf8v*)(c2b + (((w * 2 + nt) * 4 + ks) * 64 + lane) * 8);
            acc[nt] = MFMA(af[ks], b, acc[nt]);
        }
    #pragma unroll
    for (int nt = 0; nt < 2; nt++) {
        int n = w * 32 + nt * 16 + lc;
        float bb = cb2cv[l * HC + n];
        #pragma unroll
        for (int r = 0; r < 4; r++)
            srow[quad * 4 + r][n] = f2b(silu(acc[nt][r] + bb));
    }
    __syncthreads();   // af loads drained before re-zero (barrier = memory fence)
    // re-zero this block's msum rows for the next layer's scatter
    {
        int zr = tid >> 4, zc = (tid & 15) * 8;
        *(f4v*)(msum + (size_t)(m0 + zr) * HC + zc) = zero;
        *(f4v*)(msum + (size_t)(m0 + zr) * HC + zc + 4) = zero;
    }
    bf8v a2[4];
    #pragma unroll
    for (int ks = 0; ks < 4; ks++)
        a2[ks] = *(const bf8v*)&srow[lc][ks * 32 + quad * 8];
    __syncthreads();   // srow reused for nv below
    f4v acc2[2] = {zero, zero};
    const bf16* lwb = lwp + (size_t)l * 16384;
    #pragma unroll
    for (int nt = 0; nt < 2; nt++)
        #pragma unroll
        for (int ks = 0; ks < 4; ks++) {
            bf8v b = *(const bf8v*)(lwb + (((w * 2 + nt) * 4 + ks) * 64 + lane) * 8);
            acc2[nt] = MFMA(a2[ks], b, acc2[nt]);
        }
    int isf = (isf_arg >= 0) ? isf_arg : isf_of(flagp);
    #pragma unroll
    for (int nt = 0; nt < 2; nt++) {
        int n = w * 32 + nt * 16 + lc;
        float bb = lbcv[l * HC + n];
        #pragma unroll
        for (int r = 0; r < 4; r++) {
            int row = m0 + quad * 4 + r;
            size_t o = (size_t)row * HC + n;
            float nv = x[o] + acc2[nt][r] + bb;
            if (!last) {
                x[o] = nv;
                xb[o] = f2b(nv);
            } else {
                if (isf) ((float*)out)[o] = nv;
                else     ((bf16*)out)[o] = f2b(nv);
            }
            srow[quad * 4 + r][n] = f2b(nv);
        }
    }
    if (do_y) {
        __syncthreads();
        bf8v a3[4];
        #pragma unroll
        for (int ks = 0; ks < 4; ks++)
            a3[ks] = *(const bf8v*)&srow[lc][ks * 32 + quad * 8];
        f4v acc3[2] = {zero, zero};
        const bf16* c1b = cw1p + (size_t)(l + 1) * 16384;
        #pragma unroll
        for (int nt = 0; nt < 2; nt++)
            #pragma unroll
            for (int ks = 0; ks < 4; ks++) {
                bf8v b = *(const bf8v*)(c1b + (((w * 2 + nt) * 4 + ks) * 64 + lane) * 8);
                acc3[nt] = MFMA(a3[ks], b, acc3[nt]);
            }
        #pragma unroll
        for (int nt = 0; nt < 2; nt++) {
            int n = w * 32 + nt * 16 + lc;
            #pragma unroll
            for (int r = 0; r < 4; r++) {
                int row = m0 + quad * 4 + r;
                ybf[(size_t)row * HC + n] = f2b(acc3[nt][r]);
            }
        }
    }
}

// ---------------- launch ----------------
extern "C" void kernel_launch(void* const* d_in, const int* in_sizes, int n_in,
                              void* d_out, int out_size, void* d_ws, size_t ws_size,
                              hipStream_t stream) {
    const int*  z      = (const int*) d_in[0];
    const void* pos    = d_in[1];
    const int*  ei     = (const int*) d_in[3];
    const void* emb    = d_in[4];
    const void* nbremb = d_in[5];
    const void* Wp     = d_in[6];
    const void* bp     = d_in[7];
    const void* Wc     = d_in[8];
    const void* bc     = d_in[9];
    const void* means  = d_in[10];
    const void* betas  = d_in[11];
    const void* W1     = d_in[12];
    const void* b1     = d_in[13];
    const void* W2     = d_in[14];
    const void* b2     = d_in[15];
    const void* cW1    = d_in[16];
    const void* cW2    = d_in[17];
    const void* cb2    = d_in[18];
    const void* lW     = d_in[19];
    const void* lb     = d_in[20];

    char* p = (char*)d_ws;
    auto alloc = [&](size_t bytes) { char* r = p; p += (bytes + 255) / 256 * 256; return r; };
    // flag | counts | msum | msg | kidx | src_s | dst_s CONTIGUOUS -> one memset
    // zeroes pads too (pad edge: kidx=0 -> Tb row 0 (=0), src=0, dst=0; pads are a
    // suffix of any 64-edge window -> always first/last segment -> atomicAdd(+0.0)).
    int*   flag    = (int*)  alloc(256);
    int*   counts  = (int*)  alloc((size_t)NATOMS * 4);
    float* msum    = (float*)alloc((size_t)NATOMS * HC * 4);
    float* msg     = (float*)alloc((size_t)NATOMS * HC * 4);
    int*   kidx_s  = (int*)  alloc((size_t)NEDGES * 4);
    int*   src_s   = (int*)  alloc((size_t)NEDGES * 4);
    int*   dst_s   = (int*)  alloc((size_t)NEDGES * 4);
    char*  zend    = p;
    int*   rowptr  = (int*)  alloc((size_t)(NATOMS + 1) * 4);
    int*   cursor  = (int*)  alloc((size_t)NATOMS * 4);
    float* d_raw   = (float*)alloc((size_t)NEDGES * 4);
    float* x       = (float*)alloc((size_t)NATOMS * HC * 4);
    bf16*  xb      = (bf16*) alloc((size_t)NATOMS * HC * 2);
    bf16*  ybf     = (bf16*) alloc((size_t)NATOMS * HC * 2);
    bf16*  Tb      = (bf16*) alloc((size_t)(NLAY + 1) * NK * HC * 2);  // 14.7 MB
    bf16*  wpp     = (bf16*) alloc((size_t)8192 * 2);
    bf16*  wcp     = (bf16*) alloc((size_t)32768 * 2);
    bf16*  w1p     = (bf16*) alloc((size_t)NLAY * 8192 * 2);
    bf16*  w2p     = (bf16*) alloc((size_t)NLAY * 16384 * 2);
    bf16*  cw1p    = (bf16*) alloc((size_t)NLAY * 16384 * 2);
    bf16*  cw2p    = (bf16*) alloc((size_t)NLAY * 16384 * 2);
    bf16*  lwp     = (bf16*) alloc((size_t)NLAY * 16384 * 2);
    bf16*  nbrembbf= (bf16*) alloc((size_t)MAXZ_ * HC * 2);
    float* bpcv    = (float*)alloc((size_t)HC * 4);
    float* bccv    = (float*)alloc((size_t)HC * 4);
    float* b1cv    = (float*)alloc((size_t)NLAY * HC * 4);
    float* b2cv    = (float*)alloc((size_t)NLAY * HC * 4);
    float* cb2cv   = (float*)alloc((size_t)NLAY * HC * 4);
    float* lbcv    = (float*)alloc((size_t)NLAY * HC * 4);
    float* meanscv = (float*)alloc((size_t)RBF * 4);
    float* betascv = (float*)alloc((size_t)RBF * 4);

    // host-side dtype detection: confirm bytes semantics via z (int32, NATOMS*4),
    // then pos bytes distinguish f32 (NATOMS*3*4) vs bf16 (NATOMS*3*2).
    int isf_host = -1;
    if (in_sizes != nullptr && n_in > 1 && in_sizes[0] == NATOMS * 4) {
        if      (in_sizes[1] == NATOMS * 3 * 4) isf_host = 1;
        else if (in_sizes[1] == NATOMS * 3 * 2) isf_host = 0;
    }

    hipMemsetAsync(flag, 0, (size_t)(zend - (char*)flag), stream);
    if (isf_host < 0) {
        probe_k<<<(NATOMS * 3 + 255) / 256, 256, 0, stream>>>(pos, flag);
    } else if (isf_host == 1) {
        // flag := 0x7F7F7F7F -> float ~3.4e38 > 1e4 -> isf_of()==1 (fallback readers)
        hipMemsetAsync(flag, 0x7F, 4, stream);
    }

    setup1_k<<<EG + 300, 256, 0, stream>>>(ei, pos, flag, isf_host, counts, d_raw,
                                           Wp, Wc, W1, W2, cW1, cW2, lW, means, betas,
                                           bp, bc, b1, b2, cb2, lb, nbremb,
                                           wpp, wcp, w1p, w2p, cw1p, cw2p, lwp,
                                           meanscv, betascv, bpcv, bccv, b1cv, b2cv,
                                           cb2cv, lbcv, nbrembbf);
    scan_k<<<1, 1024, 0, stream>>>(counts, rowptr, cursor);
    setup2_k<<<EG + TBGRID, 256, 0, stream>>>(ei, d_raw, cursor, kidx_s, src_s, dst_s,
                                              wpp, bpcv, w1p, b1cv, w2p, b2cv,
                                              meanscv, betascv, Tb);

    nbr_tab_k<<<EGRID, 256, 0, stream>>>(rowptr, kidx_s, src_s, dst_s, z, nbrembbf,
                                         Tb, msg);
    combine_k<<<YGRID, 256, 0, stream>>>(z, emb, msg, wcp, bccv, cw1p, flag, isf_host,
                                         x, xb, ybf);

    for (int l = 0; l < NLAY; l++) {
        filt_tab_k<<<EGRID, 256, 0, stream>>>(l, rowptr, kidx_s, src_s, dst_s, ybf,
                                              Tb, msum);
        int lastl = (l == NLAY - 1) ? 1 : 0;
        upd_mfma_k<<<UGRID, 256, 0, stream>>>(msum, l, cw2p, cb2cv, lwp, lbcv,
                                              cw1p, lastl ? 0 : 1, lastl,
                                              x, xb, ybf, d_out, flag, isf_host);
    }
}

// Round 9
// 334.362 us; speedup vs baseline: 5.3558x; 1.0095x over previous
//
#include <hip/hip_runtime.h>
#include <hip/hip_bf16.h>

// TorchMD_GN_Ext R21: exact revert to R17 (green, 333.9us).
// R20's CSR-gather rewrite passed phase-1 correctness but diverged post-timing
// (replay-state sensitivity, mechanism not identified) AND showed zero speed
// delta -- the edge kernels were never the dominant cost. Reverting to the
// best-known green structure.
//  - permgeom precomputes kidx (table row, int); ed_s deleted
//  - seg_mfma slot_s loads vectorized (2x int4)
//  19 kernel dispatches + 1 memset.

#define NATOMS 10000
#define NEDGES 320000
#define HC 128
#define RBF 50
#define NLAY 6
#define MAXZ_ 100
#define NK 8192
#define EG 1250                     // (NEDGES+255)/256
#define TBGRID (7 * (NK / 64))      // 896
#define EGRID (NEDGES / 64)         // 5000 worst case; blocks early-exit past Eact
#define YGRID ((NATOMS + 63) / 64)  // 157
#define UGRID (NATOMS / 16)         // 625 (NATOMS % 16 == 0)

typedef __hip_bfloat16 bf16;
typedef __attribute__((ext_vector_type(8))) short bf8v;
typedef __attribute__((ext_vector_type(4))) float f4v;
typedef __attribute__((ext_vector_type(4))) int i4v;

__device__ __forceinline__ float b2f(bf16 v) { return __bfloat162float(v); }
__device__ __forceinline__ bf16  f2b(float v) { return __float2bfloat16(v); }
__device__ __forceinline__ short f2s(float v) { bf16 h = f2b(v); return *(short*)&h; }
__device__ __forceinline__ float s2f(unsigned short s) {
    return __int_as_float(((int)s) << 16);
}
__device__ __forceinline__ float silu(float v) {
    return v * __builtin_amdgcn_rcpf(1.0f + __expf(-v));
}
__device__ __forceinline__ int isf_of(const int* flagp) {
    return (__int_as_float(flagp[0]) > 1.0e4f) ? 1 : 0;
}

template<int ISF>
__device__ __forceinline__ float LD(const void* p, size_t i) {
    if (ISF) return ((const float*)p)[i];
    return b2f(((const bf16*)p)[i]);
}

// 8 consecutive f32 -> bf8v via two dwordx4 loads (same rounding as scalar path)
__device__ __forceinline__ bf8v f32x8_to_b(const float* p) {
    f4v v0 = *(const f4v*)p;
    f4v v1 = *(const f4v*)(p + 4);
    bf8v r;
    r[0] = f2s(v0[0]); r[1] = f2s(v0[1]); r[2] = f2s(v0[2]); r[3] = f2s(v0[3]);
    r[4] = f2s(v1[0]); r[5] = f2s(v1[1]); r[6] = f2s(v1[2]); r[7] = f2s(v1[3]);
    return r;
}
template<int ISF>
__device__ __forceinline__ bf8v LD8(const void* p, size_t i) {
    if (ISF) return f32x8_to_b((const float*)p + i);
    return *(const bf8v*)((const bf16*)p + i);
}

__device__ __forceinline__ int clampN(int v) {
    return v < 0 ? 0 : (v >= NATOMS ? NATOMS - 1 : v);
}

// edge distance (computed once, in histd; cached to d_raw for permgeom)
template<int ISF>
__device__ __forceinline__ float edge_d(const int* __restrict__ ei,
                                        const void* __restrict__ pos, int e,
                                        int* sOut, int* tOut) {
    int s = clampN(ei[e]);
    int t = clampN(ei[NEDGES + e]);
    *sOut = s; *tOut = t;
    float dx = LD<ISF>(pos, (size_t)s * 3 + 0) - LD<ISF>(pos, (size_t)t * 3 + 0);
    float dy = LD<ISF>(pos, (size_t)s * 3 + 1) - LD<ISF>(pos, (size_t)t * 3 + 1);
    float dz = LD<ISF>(pos, (size_t)s * 3 + 2) - LD<ISF>(pos, (size_t)t * 3 + 2);
    float d = sqrtf(dx * dx + dy * dy + dz * dz + 1e-12f);
    if (d != d) d = 1e30f;
    return d;
}

// ---------------- dtype probe ----------------
__global__ void probe_k(const void* pos, int* flag) {
    int i = blockIdx.x * 256 + threadIdx.x;
    float v = 0.0f;
    if (i < NATOMS * 3) {
        v = fabsf(b2f(((const bf16*)pos)[i]));
        if (v != v) v = 1e30f;
    }
    #pragma unroll
    for (int off = 32; off > 0; off >>= 1)
        v = fmaxf(v, __shfl_xor(v, off, 64));
    if ((threadIdx.x & 63) == 0) atomicMax(flag, __float_as_int(v));
}

// ------- histogram of ACTIVE (d<5) edges + d cache -------
template<int ISF>
__device__ __forceinline__ void histd_body(int b, int tid, const int* __restrict__ ei,
                                           const void* __restrict__ pos,
                                           int* __restrict__ counts,
                                           float* __restrict__ d_raw) {
    int e = b * 256 + tid;
    if (e >= NEDGES) return;
    int s, t;
    float d = edge_d<ISF>(ei, pos, e, &s, &t);
    d_raw[e] = d;            // cache for permgeom (bit-identical d)
    if (d < 5.0f) atomicAdd(&counts[t], 1);
}

// ---------------- mega pack/convert ----------------
template<int ISF>
__device__ void packB_at(int t, const void* src, int K, int ksteps, size_t perLsrc,
                         size_t perLdst, int L, bf16* dst) {
    if (t >= L * 8 * ksteps * 64) return;
    int lane = t & 63;
    int t2 = t >> 6;
    int ks = t2 % ksteps;
    int t3 = t2 / ksteps;
    int nt = t3 & 7;
    int l  = t3 >> 3;
    int quad = lane >> 4, lc = lane & 15;
    int col = nt * 16 + lc;
    for (int j = 0; j < 8; j++) {
        int k = ks * 32 + quad * 8 + j;
        float v = (k < K) ? LD<ISF>(src, (size_t)l * perLsrc + (size_t)k * 128 + col) : 0.0f;
        dst[(size_t)l * perLdst + ((size_t)((nt * ksteps + ks) * 64 + lane)) * 8 + j] = f2b(v);
    }
}
template<int ISF>
__device__ void packB24_at(int t, const void* w2, const void* cw1, const void* cw2,
                           const void* lw, bf16* w2p, bf16* cw1p, bf16* cw2p, bf16* lwp) {
    if (t >= 24 * 8 * 4 * 64) return;
    int lane = t & 63;
    int t2 = t >> 6;
    int ks = t2 & 3;
    int t3 = t2 >> 2;
    int nt = t3 & 7;
    int m  = t3 >> 3;
    int which = m / NLAY, li = m % NLAY;
    const void* src = which == 0 ? w2 : which == 1 ? cw1 : which == 2 ? cw2 : lw;
    bf16* dst = which == 0 ? w2p : which == 1 ? cw1p : which == 2 ? cw2p : lwp;
    int quad = lane >> 4, lc = lane & 15;
    int col = nt * 16 + lc;
    #pragma unroll
    for (int j = 0; j < 8; j++) {
        int k = ks * 32 + quad * 8 + j;
        float v = LD<ISF>(src, (size_t)li * 16384 + (size_t)k * 128 + col);
        dst[(size_t)li * 16384 + ((size_t)((nt * 4 + ks) * 64 + lane)) * 8 + j] = f2b(v);
    }
}
template<int ISF>
__device__ void cvts_at(int i, const void* means, const void* betas, const void* bp,
                        const void* bc, const void* b1, const void* b2,
                        const void* cb2, const void* lb,
                        float* meanscv, float* betascv, float* bpcv, float* bccv,
                        float* b1cv, float* b2cv, float* cb2cv, float* lbcv) {
    if      (i < 50)   meanscv[i]        = LD<ISF>(means, i);
    else if (i < 100)  betascv[i - 50]   = LD<ISF>(betas, i - 50);
    else if (i < 228)  bpcv[i - 100]     = LD<ISF>(bp, i - 100);
    else if (i < 356)  bccv[i - 228]     = LD<ISF>(bc, i - 228);
    else if (i < 1124) b1cv[i - 356]     = LD<ISF>(b1, i - 356);
    else if (i < 1892) b2cv[i - 1124]    = LD<ISF>(b2, i - 1124);
    else if (i < 2660) cb2cv[i - 1892]   = LD<ISF>(cb2, i - 1892);
    else if (i < 3428) lbcv[i - 2660]    = LD<ISF>(lb, i - 2660);
}
template<int ISF>
__device__ void packall_body(int b, int tid, const void* Wp, const void* Wc, const void* W1,
                             const void* W2, const void* cW1, const void* cW2,
                             const void* lW, const void* means, const void* betas,
                             const void* bp, const void* bc, const void* b1,
                             const void* b2, const void* cb2, const void* lb,
                             const void* nbremb,
                             bf16* wpp, bf16* wcp, bf16* w1p, bf16* w2p, bf16* cw1p,
                             bf16* cw2p, bf16* lwp, float* meanscv, float* betascv,
                             float* bpcv, float* bccv, float* b1cv, float* b2cv,
                             float* cb2cv, float* lbcv, bf16* nbrembbf) {
    if (b < 4)        packB_at<ISF>(b * 256 + tid, Wp, RBF, 2, 6400, 8192, 1, wpp);
    else if (b < 20)  packB_at<ISF>((b - 4) * 256 + tid, Wc, 256, 8, 32768, 32768, 1, wcp);
    else if (b < 44)  packB_at<ISF>((b - 20) * 256 + tid, W1, RBF, 2, 6400, 8192, NLAY, w1p);
    else if (b < 236) packB24_at<ISF>((b - 44) * 256 + tid, W2, cW1, cW2, lW,
                                      w2p, cw1p, cw2p, lwp);
    else if (b < 250) cvts_at<ISF>((b - 236) * 256 + tid, means, betas, bp, bc, b1, b2,
                                   cb2, lb, meanscv, betascv, bpcv, bccv,
                                   b1cv, b2cv, cb2cv, lbcv);
    else {
        int i = (b - 250) * 256 + tid;
        if (i < MAXZ_ * HC) nbrembbf[i] = f2b(LD<ISF>(nbremb, i));
    }
}

// -------- setup1: histd (blocks 0..1249) + packall (blocks 1250..1549) --------
__global__ __launch_bounds__(256)
void setup1_k(const int* ei, const void* pos, const int* flagp,
              int* counts, float* d_raw,
              const void* Wp, const void* Wc, const void* W1,
              const void* W2, const void* cW1, const void* cW2,
              const void* lW, const void* means, const void* betas,
              const void* bp, const void* bc, const void* b1,
              const void* b2, const void* cb2, const void* lb,
              const void* nbremb,
              bf16* wpp, bf16* wcp, bf16* w1p, bf16* w2p, bf16* cw1p,
              bf16* cw2p, bf16* lwp, float* meanscv, float* betascv,
              float* bpcv, float* bccv, float* b1cv, float* b2cv,
              float* cb2cv, float* lbcv, bf16* nbrembbf) {
    int b = blockIdx.x, tid = threadIdx.x;
    int isf = isf_of(flagp);
    if (b < EG) {
        if (isf) histd_body<1>(b, tid, ei, pos, counts, d_raw);
        else     histd_body<0>(b, tid, ei, pos, counts, d_raw);
    } else {
        b -= EG;
        if (isf) packall_body<1>(b, tid, Wp, Wc, W1, W2, cW1, cW2, lW, means, betas,
                                 bp, bc, b1, b2, cb2, lb, nbremb, wpp, wcp,
                                 w1p, w2p, cw1p, cw2p, lwp, meanscv, betascv,
                                 bpcv, bccv, b1cv, b2cv, cb2cv, lbcv, nbrembbf);
        else     packall_body<0>(b, tid, Wp, Wc, W1, W2, cW1, cW2, lW, means, betas,
                                 bp, bc, b1, b2, cb2, lb, nbremb, wpp, wcp,
                                 w1p, w2p, cw1p, cw2p, lwp, meanscv, betascv,
                                 bpcv, bccv, b1cv, b2cv, cb2cv, lbcv, nbrembbf);
    }
}

// ---------------- scan (one-pass: 10 elems/thread) ----------------
__global__ void scan_k(const int* __restrict__ counts, int* __restrict__ rowptr,
                       int* __restrict__ cursor) {
    __shared__ int wsum[16];
    int tid = threadIdx.x, lane = tid & 63, w = tid >> 6;
    int base = tid * 10;
    int v[10];
    int s = 0;
    #pragma unroll
    for (int j = 0; j < 10; j++) {
        int i = base + j;
        int c = (i < NATOMS) ? counts[i] : 0;
        v[j] = c; s += c;
    }
    int si = s;
    #pragma unroll
    for (int off = 1; off < 64; off <<= 1) {
        int t = __shfl_up(si, off, 64);
        if (lane >= off) si += t;
    }
    if (lane == 63) wsum[w] = si;
    __syncthreads();
    if (w == 0 && lane < 16) {
        int t = wsum[lane];
        int s2 = t;
        #pragma unroll
        for (int off = 1; off < 16; off <<= 1) {
            int u = __shfl_up(s2, off, 64);
            if (lane >= off) s2 += u;
        }
        wsum[lane] = s2 - t;   // exclusive wave prefix
    }
    __syncthreads();
    int run = wsum[w] + si - s;   // exclusive prefix of this thread's chunk
    #pragma unroll
    for (int j = 0; j < 10; j++) {
        int i = base + j;
        if (i < NATOMS) {
            cursor[i] = run;
            run += v[j];
            rowptr[i + 1] = run;
        }
    }
    if (tid == 0) rowptr[0] = 0;
}

// ---------------- MFMA helpers ----------------
#define MFMA(a, b, c) __builtin_amdgcn_mfma_f32_16x16x32_bf16((a), (b), (c), 0, 0, 0)

// ---------- permgeom body (blocks 0..1249 of setup2) ----------
__device__ __forceinline__ void permgeom_body(int b, int tid, const int* __restrict__ ei,
                                              const float* __restrict__ d_raw,
                                              int* __restrict__ cursor,
                                              int* __restrict__ kidx_s,
                                              int* __restrict__ src_s,
                                              int* __restrict__ dst_s) {
    int e = b * 256 + tid;
    if (e >= NEDGES) return;
    float d = d_raw[e];
    if (d >= 5.0f) return;                  // dead edge: exactly 0 contribution
    int s = clampN(ei[e]);
    int t = clampN(ei[NEDGES + e]);
    int p = atomicAdd(&cursor[t], 1);
    float ed = __expf(-d);
    // identical formula to the old per-kernel k computation (bit-identical k)
    float pos = fminf(fmaxf(ed * (float)(NK - 1) + 0.5f, 0.0f), (float)(NK - 1));
    kidx_s[p] = (int)pos;
    src_s[p] = s;
    dst_s[p] = t;
}

// ---------- tabbuild body (blocks 1250.. of setup2) ----------
__device__ __forceinline__ void tabbuild_body(int bb, int tid,
                const bf16* __restrict__ wpp, const float* __restrict__ bpcv,
                const bf16* __restrict__ w1p, const float* __restrict__ b1cv,
                const bf16* __restrict__ w2p, const float* __restrict__ b2cv,
                const float* __restrict__ meanscv, const float* __restrict__ betascv,
                bf16* __restrict__ Tb) {
    __shared__ bf16 hid[64][136];
    __shared__ float csh[64], edsh[64];
    int f = bb >> 7, kb = bb & 127;
    int base = kb * 64;
    int wave = tid >> 6, lane = tid & 63, quad = lane >> 4, lc = lane & 15;
    if (tid < 64) {
        float ed = (float)(base + tid) * (1.0f / (NK - 1));
        float d = -logf(fmaxf(ed, 1e-30f));
        float C = (d < 5.0f) ? 0.5f * (__cosf(d * 0.6283185307f) + 1.0f) : 0.0f;
        csh[tid] = C; edsh[tid] = ed;
    }
    __syncthreads();
    float edi = edsh[wave * 16 + lc], Ci = csh[wave * 16 + lc];
    bf8v af[2];
    #pragma unroll
    for (int ks = 0; ks < 2; ks++) {
        #pragma unroll
        for (int j = 0; j < 8; j++) {
            int r = ks * 32 + quad * 8 + j;
            float v = 0.0f;
            if (r < RBF) { float u = edi - meanscv[r]; v = Ci * __expf(-betascv[r] * u * u); }
            af[ks][j] = f2s(v);
        }
    }
    f4v zero = {0.f, 0.f, 0.f, 0.f};
    f4v acc[8];
    #pragma unroll
    for (int nt = 0; nt < 8; nt++) acc[nt] = zero;
    const bf16* w1b = (f == 0) ? wpp : w1p + (size_t)(f - 1) * 8192;
    #pragma unroll
    for (int nt = 0; nt < 8; nt++)
        #pragma unroll
        for (int ks = 0; ks < 2; ks++) {
            bf8v b = *(const bf8v*)(w1b + ((nt * 2 + ks) * 64 + lane) * 8);
            acc[nt] = MFMA(af[ks], b, acc[nt]);
        }
    if (f == 0) {
        #pragma unroll
        for (int nt = 0; nt < 8; nt++) {
            int n = nt * 16 + lc;
            float bb2 = bpcv[n];
            #pragma unroll
            for (int r = 0; r < 4; r++) {
                int row = wave * 16 + quad * 4 + r;
                Tb[(size_t)(base + row) * HC + n] = f2b((acc[nt][r] + bb2) * csh[row]);
            }
        }
        return;
    }
    int l = f - 1;
    #pragma unroll
    for (int nt = 0; nt < 8; nt++) {
        int n = nt * 16 + lc;
        float bb2 = b1cv[l * HC + n];
        #pragma unroll
        for (int r = 0; r < 4; r++)
            hid[wave * 16 + quad * 4 + r][n] = f2b(silu(acc[nt][r] + bb2));
    }
    __syncthreads();
    bf8v a2[4];
    #pragma unroll
    for (int ks = 0; ks < 4; ks++)
        a2[ks] = *(const bf8v*)&hid[wave * 16 + lc][ks * 32 + quad * 8];
    f4v acc2[8];
    #pragma unroll
    for (int nt = 0; nt < 8; nt++) acc2[nt] = zero;
    const bf16* w2b = w2p + (size_t)l * 16384;
    #pragma unroll
    for (int nt = 0; nt < 8; nt++)
        #pragma unroll
        for (int ks = 0; ks < 4; ks++) {
            bf8v b = *(const bf8v*)(w2b + ((nt * 4 + ks) * 64 + lane) * 8);
            acc2[nt] = MFMA(a2[ks], b, acc2[nt]);
        }
    #pragma unroll
    for (int nt = 0; nt < 8; nt++) {
        int n = nt * 16 + lc;
        float bb2 = b2cv[l * HC + n];
        #pragma unroll
        for (int r = 0; r < 4; r++) {
            int row = wave * 16 + quad * 4 + r;
            Tb[((size_t)f * NK + base + row) * HC + n] = f2b((acc2[nt][r] + bb2) * csh[row]);
        }
    }
}

// -------- setup2: permgeom (blocks 0..1249) + tabbuild (blocks 1250..2145) --------
__global__ __launch_bounds__(256)
void setup2_k(const int* ei, const float* d_raw, int* cursor,
              int* kidx_s, int* src_s, int* dst_s,
              const bf16* wpp, const float* bpcv,
              const bf16* w1p, const float* b1cv,
              const bf16* w2p, const float* b2cv,
              const float* meanscv, const float* betascv, bf16* Tb) {
    int b = blockIdx.x, tid = threadIdx.x;
    if (b < EG) permgeom_body(b, tid, ei, d_raw, cursor, kidx_s, src_s, dst_s);
    else        tabbuild_body(b - EG, tid, wpp, bpcv, w1p, b1cv, w2p, b2cv,
                              meanscv, betascv, Tb);
}

// ---------------- segment helpers ----------------
__device__ __forceinline__ void seg_prep(const int* __restrict__ dst_s, int i0, int tid,
                                         int* ddst, int* slot_s, int* distinct_s,
                                         int* nseg_s) {
    if (tid < 64) {
        int d = dst_s[i0 + tid];
        ddst[tid] = d;
        int dprev = __shfl_up(d, 1, 64);
        int flag = (tid == 0 || d != dprev) ? 1 : 0;
        int s = flag;
        #pragma unroll
        for (int off = 1; off < 64; off <<= 1) {
            int t = __shfl_up(s, off, 64);
            if (tid >= off) s += t;
        }
        slot_s[tid] = s - 1;
        if (flag) distinct_s[s - 1] = d;
        if (tid == 63) *nseg_s = s;
    }
}

__device__ __forceinline__ void seg_mfma(const bf16 (*mvT)[72], const int* ddst,
                                         const int* slot_s, const int* distinct_s,
                                         int nseg, float* __restrict__ out, int tid) {
    int wave = tid >> 6, lane = tid & 63, quad = lane >> 4, lc = lane & 15;
    if (nseg <= 16) {
        bf8v sa[2];
        #pragma unroll
        for (int ks = 0; ks < 2; ks++) {
            int k0 = ks * 32 + quad * 8;
            i4v s0 = *(const i4v*)&slot_s[k0];
            i4v s1 = *(const i4v*)&slot_s[k0 + 4];
            #pragma unroll
            for (int j = 0; j < 4; j++) {
                sa[ks][j]     = (s0[j] == lc) ? (short)0x3F80 : (short)0;
                sa[ks][j + 4] = (s1[j] == lc) ? (short)0x3F80 : (short)0;
            }
        }
        f4v z4 = {0.f, 0.f, 0.f, 0.f};
        f4v sacc[2] = {z4, z4};
        #pragma unroll
        for (int nt = 0; nt < 2; nt++)
            #pragma unroll
            for (int ks = 0; ks < 2; ks++) {
                bf8v b = *(const bf8v*)&mvT[wave * 32 + nt * 16 + lc][ks * 32 + quad * 8];
                sacc[nt] = MFMA(sa[ks], b, sacc[nt]);
            }
        #pragma unroll
        for (int nt = 0; nt < 2; nt++)
            #pragma unroll
            for (int r = 0; r < 4; r++) {
                int sl = quad * 4 + r;
                if (sl < nseg) {
                    int atom = distinct_s[sl];
                    int n = wave * 32 + nt * 16 + lc;
                    float v = sacc[nt][r];
                    if (sl == 0 || sl == nseg - 1)
                        atomicAdd(&out[(size_t)atom * HC + n], v);
                    else
                        out[(size_t)atom * HC + n] = v;
                }
            }
    } else {
        int col = tid & 127;
        int base = (tid >> 7) * 32;
        int cur = ddst[base];
        float s = 0.0f;
        bool first = true;
        for (int e = base; e < base + 32; e++) {
            int dn = ddst[e];
            if (dn != cur) {
                if (first) atomicAdd(&out[(size_t)cur * HC + col], s);
                else out[(size_t)cur * HC + col] = s;
                first = false; cur = dn; s = 0.0f;
            }
            s += b2f(mvT[col][e]);
        }
        atomicAdd(&out[(size_t)cur * HC + col], s);
    }
}

// ---------------- neighbor edges ----------------
__global__ __launch_bounds__(256)
void nbr_tab_k(const int* __restrict__ rowptr,
               const int* __restrict__ kidx_s, const int* __restrict__ src_s,
               const int* __restrict__ dst_s, const int* __restrict__ z,
               const bf16* __restrict__ nbrembbf, const bf16* __restrict__ Tb,
               float* __restrict__ msg) {
    __shared__ bf16 mvT[128][72];
    __shared__ int ddst[64], slot_s[64], distinct_s[64];
    __shared__ int nseg_s;
    int i0 = blockIdx.x * 64;
    if (i0 >= rowptr[NATOMS]) return;
    int tid = threadIdx.x;
    seg_prep(dst_s, i0, tid, ddst, slot_s, distinct_s, &nseg_s);
    int row = tid & 63, c0 = (tid >> 6) * 32;
    int e = i0 + row;
    int s = src_s[e];
    float msk = (s != dst_s[e]) ? 1.0f : 0.0f;
    int k = kidx_s[e];
    const bf8v* tp = (const bf8v*)(Tb + (size_t)k * HC + c0);
    bf8v tv[4];
    #pragma unroll
    for (int g = 0; g < 4; g++) tv[g] = tp[g];
    int zz = z[s]; zz = zz < 0 ? 0 : (zz >= MAXZ_ ? MAXZ_ - 1 : zz);
    const bf8v* ep = (const bf8v*)(nbrembbf + (size_t)zz * HC + c0);
    bf8v ev[4];
    #pragma unroll
    for (int g = 0; g < 4; g++) ev[g] = ep[g];
    #pragma unroll
    for (int g = 0; g < 4; g++)
        #pragma unroll
        for (int m = 0; m < 8; m++) {
            float v = s2f((unsigned short)tv[g][m]) * msk *
                      s2f((unsigned short)ev[g][m]);
            mvT[c0 + g * 8 + m][row] = f2b(v);
        }
    __syncthreads();
    seg_mfma(mvT, ddst, slot_s, distinct_s, nseg_s, msg, tid);
}

// ---------------- combine (prep fused) ----------------
template<int ISF>
__device__ void combine_body(const int* __restrict__ z, const void* __restrict__ emb,
                             const float* __restrict__ msg, const bf16* __restrict__ wcp,
                             const float* __restrict__ bccv, const bf16* __restrict__ cw1b,
                             float* __restrict__ x, bf16* __restrict__ xb,
                             bf16* __restrict__ ybf) {
    __shared__ bf16 srow[64][136];
    int tid = threadIdx.x;
    int wave = tid >> 6, lane = tid & 63, quad = lane >> 4, lc = lane & 15;
    int m0 = blockIdx.x * 64;
    int arow = m0 + wave * 16 + lc;
    int rowc = arow < NATOMS ? arow : NATOMS - 1;
    int zz = z[rowc]; zz = zz < 0 ? 0 : (zz >= MAXZ_ ? MAXZ_ - 1 : zz);
    bf8v af[8];
    #pragma unroll
    for (int ks = 0; ks < 4; ks++)
        af[ks] = LD8<ISF>(emb, (size_t)zz * HC + ks * 32 + quad * 8);
    #pragma unroll
    for (int ks = 4; ks < 8; ks++)
        af[ks] = f32x8_to_b(msg + (size_t)rowc * HC + (ks - 4) * 32 + quad * 8);
    f4v zero = {0.f, 0.f, 0.f, 0.f};
    f4v acc[8];
    #pragma unroll
    for (int nt = 0; nt < 8; nt++) acc[nt] = zero;
    #pragma unroll
    for (int nt = 0; nt < 8; nt++)
        #pragma unroll
        for (int ks = 0; ks < 8; ks++) {
            bf8v b = *(const bf8v*)(wcp + ((nt * 8 + ks) * 64 + lane) * 8);
            acc[nt] = MFMA(af[ks], b, acc[nt]);
        }
    #pragma unroll
    for (int nt = 0; nt < 8; nt++) {
        int n = nt * 16 + lc;
        float bb = bccv[n];
        #pragma unroll
        for (int r = 0; r < 4; r++) {
            int row = m0 + wave * 16 + quad * 4 + r;
            float v = acc[nt][r] + bb;
            bf16 vb = f2b(v);
            srow[wave * 16 + quad * 4 + r][n] = vb;
            if (row < NATOMS) {
                x[(size_t)row * HC + n] = v;
                xb[(size_t)row * HC + n] = vb;
            }
        }
    }
    __syncthreads();
    bf8v a3[4];
    #pragma unroll
    for (int ks = 0; ks < 4; ks++)
        a3[ks] = *(const bf8v*)&srow[wave * 16 + lc][ks * 32 + quad * 8];
    f4v acc3[8];
    #pragma unroll
    for (int nt = 0; nt < 8; nt++) acc3[nt] = zero;
    #pragma unroll
    for (int nt = 0; nt < 8; nt++)
        #pragma unroll
        for (int ks = 0; ks < 4; ks++) {
            bf8v b = *(const bf8v*)(cw1b + ((nt * 4 + ks) * 64 + lane) * 8);
            acc3[nt] = MFMA(a3[ks], b, acc3[nt]);
        }
    #pragma unroll
    for (int nt = 0; nt < 8; nt++) {
        int n = nt * 16 + lc;
        #pragma unroll
        for (int r = 0; r < 4; r++) {
            int row = m0 + wave * 16 + quad * 4 + r;
            if (row < NATOMS) ybf[(size_t)row * HC + n] = f2b(acc3[nt][r]);
        }
    }
}
__global__ __launch_bounds__(256)
void combine_k(const int* z, const void* emb, const float* msg, const bf16* wcp,
               const float* bccv, const bf16* cw1b, const int* flagp,
               float* x, bf16* xb, bf16* ybf) {
    if (isf_of(flagp)) combine_body<1>(z, emb, msg, wcp, bccv, cw1b, x, xb, ybf);
    else               combine_body<0>(z, emb, msg, wcp, bccv, cw1b, x, xb, ybf);
}

// ---------------- filter edges ----------------
__global__ __launch_bounds__(256)
void filt_tab_k(int l, const int* __restrict__ rowptr,
                const int* __restrict__ kidx_s, const int* __restrict__ src_s,
                const int* __restrict__ dst_s, const bf16* __restrict__ ybf,
                const bf16* __restrict__ Tb, float* __restrict__ msum) {
    __shared__ bf16 mvT[128][72];
    __shared__ int ddst[64], slot_s[64], distinct_s[64];
    __shared__ int nseg_s;
    int i0 = blockIdx.x * 64;
    if (i0 >= rowptr[NATOMS]) return;
    int tid = threadIdx.x;
    seg_prep(dst_s, i0, tid, ddst, slot_s, distinct_s, &nseg_s);
    int row = tid & 63, c0 = (tid >> 6) * 32;
    int e = i0 + row;
    int k = kidx_s[e];
    const bf8v* tp = (const bf8v*)(Tb + ((size_t)(l + 1) * NK + k) * HC + c0);
    bf8v tv[4];
    #pragma unroll
    for (int g = 0; g < 4; g++) tv[g] = tp[g];
    const bf8v* yp = (const bf8v*)(ybf + (size_t)src_s[e] * HC + c0);
    bf8v yv[4];
    #pragma unroll
    for (int g = 0; g < 4; g++) yv[g] = yp[g];
    #pragma unroll
    for (int g = 0; g < 4; g++)
        #pragma unroll
        for (int m = 0; m < 8; m++) {
            float v = s2f((unsigned short)tv[g][m]) * s2f((unsigned short)yv[g][m]);
            mvT[c0 + g * 8 + m][row] = f2b(v);
        }
    __syncthreads();
    seg_mfma(mvT, ddst, slot_s, distinct_s, nseg_s, msum, tid);
}

// ---- node update, 16 rows/block (625 blocks for TLP) ----
__global__ __launch_bounds__(256)
void upd_mfma_k(float* msum, int l,
                const bf16* __restrict__ cw2p, const float* __restrict__ cb2cv,
                const bf16* __restrict__ lwp, const float* __restrict__ lbcv,
                const bf16* __restrict__ cw1p, int do_y, int last,
                float* __restrict__ x, bf16* __restrict__ xb,
                bf16* __restrict__ ybf, void* out, const int* flagp) {
    __shared__ bf16 srow[16][136];
    int tid = threadIdx.x;
    int w = tid >> 6, lane = tid & 63, quad = lane >> 4, lc = lane & 15;
    int m0 = blockIdx.x * 16;     // NATOMS % 16 == 0 -> no row guards
    bf8v af[4];
    #pragma unroll
    for (int ks = 0; ks < 4; ks++)
        af[ks] = f32x8_to_b(msum + (size_t)(m0 + lc) * HC + ks * 32 + quad * 8);
    f4v zero = {0.f, 0.f, 0.f, 0.f};
    f4v acc[2] = {zero, zero};
    const bf16* c2b = cw2p + (size_t)l * 16384;
    #pragma unroll
    for (int nt = 0; nt < 2; nt++)
        #pragma unroll
        for (int ks = 0; ks < 4; ks++) {
            bf8v b = *(const bf8v*)(c2b + (((w * 2 + nt) * 4 + ks) * 64 + lane) * 8);
            acc[nt] = MFMA(af[ks], b, acc[nt]);
        }
    #pragma unroll
    for (int nt = 0; nt < 2; nt++) {
        int n = w * 32 + nt * 16 + lc;
        float bb = cb2cv[l * HC + n];
        #pragma unroll
        for (int r = 0; r < 4; r++)
            srow[quad * 4 + r][n] = f2b(silu(acc[nt][r] + bb));
    }
    __syncthreads();   // af loads drained before re-zero (barrier = memory fence)
    // re-zero this block's msum rows for the next layer's scatter
    {
        int zr = tid >> 4, zc = (tid & 15) * 8;
        *(f4v*)(msum + (size_t)(m0 + zr) * HC + zc) = zero;
        *(f4v*)(msum + (size_t)(m0 + zr) * HC + zc + 4) = zero;
    }
    bf8v a2[4];
    #pragma unroll
    for (int ks = 0; ks < 4; ks++)
        a2[ks] = *(const bf8v*)&srow[lc][ks * 32 + quad * 8];
    __syncthreads();   // srow reused for nv below
    f4v acc2[2] = {zero, zero};
    const bf16* lwb = lwp + (size_t)l * 16384;
    #pragma unroll
    for (int nt = 0; nt < 2; nt++)
        #pragma unroll
        for (int ks = 0; ks < 4; ks++) {
            bf8v b = *(const bf8v*)(lwb + (((w * 2 + nt) * 4 + ks) * 64 + lane) * 8);
            acc2[nt] = MFMA(a2[ks], b, acc2[nt]);
        }
    int isf = isf_of(flagp);
    #pragma unroll
    for (int nt = 0; nt < 2; nt++) {
        int n = w * 32 + nt * 16 + lc;
        float bb = lbcv[l * HC + n];
        #pragma unroll
        for (int r = 0; r < 4; r++) {
            int row = m0 + quad * 4 + r;
            size_t o = (size_t)row * HC + n;
            float nv = x[o] + acc2[nt][r] + bb;
            if (!last) {
                x[o] = nv;
                xb[o] = f2b(nv);
            } else {
                if (isf) ((float*)out)[o] = nv;
                else     ((bf16*)out)[o] = f2b(nv);
            }
            srow[quad * 4 + r][n] = f2b(nv);
        }
    }
    if (do_y) {
        __syncthreads();
        bf8v a3[4];
        #pragma unroll
        for (int ks = 0; ks < 4; ks++)
            a3[ks] = *(const bf8v*)&srow[lc][ks * 32 + quad * 8];
        f4v acc3[2] = {zero, zero};
        const bf16* c1b = cw1p + (size_t)(l + 1) * 16384;
        #pragma unroll
        for (int nt = 0; nt < 2; nt++)
            #pragma unroll
            for (int ks = 0; ks < 4; ks++) {
                bf8v b = *(const bf8v*)(c1b + (((w * 2 + nt) * 4 + ks) * 64 + lane) * 8);
                acc3[nt] = MFMA(a3[ks], b, acc3[nt]);
            }
        #pragma unroll
        for (int nt = 0; nt < 2; nt++) {
            int n = w * 32 + nt * 16 + lc;
            #pragma unroll
            for (int r = 0; r < 4; r++) {
                int row = m0 + quad * 4 + r;
                ybf[(size_t)row * HC + n] = f2b(acc3[nt][r]);
            }
        }
    }
}

// ---------------- launch ----------------
extern "C" void kernel_launch(void* const* d_in, const int* in_sizes, int n_in,
                              void* d_out, int out_size, void* d_ws, size_t ws_size,
                              hipStream_t stream) {
    const int*  z      = (const int*) d_in[0];
    const void* pos    = d_in[1];
    const int*  ei     = (const int*) d_in[3];
    const void* emb    = d_in[4];
    const void* nbremb = d_in[5];
    const void* Wp     = d_in[6];
    const void* bp     = d_in[7];
    const void* Wc     = d_in[8];
    const void* bc     = d_in[9];
    const void* means  = d_in[10];
    const void* betas  = d_in[11];
    const void* W1     = d_in[12];
    const void* b1     = d_in[13];
    const void* W2     = d_in[14];
    const void* b2     = d_in[15];
    const void* cW1    = d_in[16];
    const void* cW2    = d_in[17];
    const void* cb2    = d_in[18];
    const void* lW     = d_in[19];
    const void* lb     = d_in[20];

    char* p = (char*)d_ws;
    auto alloc = [&](size_t bytes) { char* r = p; p += (bytes + 255) / 256 * 256; return r; };
    // flag | counts | msum | msg | kidx | src_s | dst_s CONTIGUOUS -> one memset
    // zeroes pads too (pad edge: kidx=0 -> Tb row 0 (=0), src=0, dst=0; pads are a
    // suffix of any 64-edge window -> always first/last segment -> atomicAdd(+0.0)).
    int*   flag    = (int*)  alloc(256);
    int*   counts  = (int*)  alloc((size_t)NATOMS * 4);
    float* msum    = (float*)alloc((size_t)NATOMS * HC * 4);
    float* msg     = (float*)alloc((size_t)NATOMS * HC * 4);
    int*   kidx_s  = (int*)  alloc((size_t)NEDGES * 4);
    int*   src_s   = (int*)  alloc((size_t)NEDGES * 4);
    int*   dst_s   = (int*)  alloc((size_t)NEDGES * 4);
    char*  zend    = p;
    int*   rowptr  = (int*)  alloc((size_t)(NATOMS + 1) * 4);
    int*   cursor  = (int*)  alloc((size_t)NATOMS * 4);
    float* d_raw   = (float*)alloc((size_t)NEDGES * 4);
    float* x       = (float*)alloc((size_t)NATOMS * HC * 4);
    bf16*  xb      = (bf16*) alloc((size_t)NATOMS * HC * 2);
    bf16*  ybf     = (bf16*) alloc((size_t)NATOMS * HC * 2);
    bf16*  Tb      = (bf16*) alloc((size_t)(NLAY + 1) * NK * HC * 2);  // 14.7 MB
    bf16*  wpp     = (bf16*) alloc((size_t)8192 * 2);
    bf16*  wcp     = (bf16*) alloc((size_t)32768 * 2);
    bf16*  w1p     = (bf16*) alloc((size_t)NLAY * 8192 * 2);
    bf16*  w2p     = (bf16*) alloc((size_t)NLAY * 16384 * 2);
    bf16*  cw1p    = (bf16*) alloc((size_t)NLAY * 16384 * 2);
    bf16*  cw2p    = (bf16*) alloc((size_t)NLAY * 16384 * 2);
    bf16*  lwp     = (bf16*) alloc((size_t)NLAY * 16384 * 2);
    bf16*  nbrembbf= (bf16*) alloc((size_t)MAXZ_ * HC * 2);
    float* bpcv    = (float*)alloc((size_t)HC * 4);
    float* bccv    = (float*)alloc((size_t)HC * 4);
    float* b1cv    = (float*)alloc((size_t)NLAY * HC * 4);
    float* b2cv    = (float*)alloc((size_t)NLAY * HC * 4);
    float* cb2cv   = (float*)alloc((size_t)NLAY * HC * 4);
    float* lbcv    = (float*)alloc((size_t)NLAY * HC * 4);
    float* meanscv = (float*)alloc((size_t)RBF * 4);
    float* betascv = (float*)alloc((size_t)RBF * 4);

    hipMemsetAsync(flag, 0, (size_t)(zend - (char*)flag), stream);
    probe_k<<<(NATOMS * 3 + 255) / 256, 256, 0, stream>>>(pos, flag);

    setup1_k<<<EG + 300, 256, 0, stream>>>(ei, pos, flag, counts, d_raw,
                                           Wp, Wc, W1, W2, cW1, cW2, lW, means, betas,
                                           bp, bc, b1, b2, cb2, lb, nbremb,
                                           wpp, wcp, w1p, w2p, cw1p, cw2p, lwp,
                                           meanscv, betascv, bpcv, bccv, b1cv, b2cv,
                                           cb2cv, lbcv, nbrembbf);
    scan_k<<<1, 1024, 0, stream>>>(counts, rowptr, cursor);
    setup2_k<<<EG + TBGRID, 256, 0, stream>>>(ei, d_raw, cursor, kidx_s, src_s, dst_s,
                                              wpp, bpcv, w1p, b1cv, w2p, b2cv,
                                              meanscv, betascv, Tb);

    nbr_tab_k<<<EGRID, 256, 0, stream>>>(rowptr, kidx_s, src_s, dst_s, z, nbrembbf,
                                         Tb, msg);
    combine_k<<<YGRID, 256, 0, stream>>>(z, emb, msg, wcp, bccv, cw1p, flag, x, xb, ybf);

    for (int l = 0; l < NLAY; l++) {
        filt_tab_k<<<EGRID, 256, 0, stream>>>(l, rowptr, kidx_s, src_s, dst_s, ybf,
                                              Tb, msum);
        int lastl = (l == NLAY - 1) ? 1 : 0;
        upd_mfma_k<<<UGRID, 256, 0, stream>>>(msum, l, cw2p, cb2cv, lwp, lbcv,
                                              cw1p, lastl ? 0 : 1, lastl,
                                              x, xb, ybf, d_out, flag);
    }
}

// Round 10
// 331.661 us; speedup vs baseline: 5.3995x; 1.0081x over previous
//
#include <hip/hip_runtime.h>
#include <hip/hip_bf16.h>

// TorchMD_GN_Ext R22: single-variable experiment on R21 (green, 334.4us):
// NK 8192 -> 4096. Theory: edge kernels are bound by Tb-row + ybf-row random
// gathers; working set (2.1MB slice + 2.5MB ybf = 4.6MB) exceeds 4MB per-XCD
// L2 -> thrash. R20's gather rewrite (no LDS/MFMA/atomics) timing identically
// supports traffic-bound, not implementation-bound. NK=4096 -> slice 1.05MB,
// set 3.5MB < 4MB -> L2-resident. Error: absmax has been exactly one bf16 ulp
// (0.03125) across all rounds incl. R20's numerics change -> rounding-dominated;
// 2x quantization step stays under the 0.0869 threshold.
//  19 kernel dispatches + 1 memset.

#define NATOMS 10000
#define NEDGES 320000
#define HC 128
#define RBF 50
#define NLAY 6
#define MAXZ_ 100
#define NK 4096
#define KB_F (NK / 64)              // tabbuild blocks per table (64)
#define EG 1250                     // (NEDGES+255)/256
#define TBGRID (7 * KB_F)           // 448
#define EGRID (NEDGES / 64)         // 5000 worst case; blocks early-exit past Eact
#define YGRID ((NATOMS + 63) / 64)  // 157
#define UGRID (NATOMS / 16)         // 625 (NATOMS % 16 == 0)

typedef __hip_bfloat16 bf16;
typedef __attribute__((ext_vector_type(8))) short bf8v;
typedef __attribute__((ext_vector_type(4))) float f4v;
typedef __attribute__((ext_vector_type(4))) int i4v;

__device__ __forceinline__ float b2f(bf16 v) { return __bfloat162float(v); }
__device__ __forceinline__ bf16  f2b(float v) { return __float2bfloat16(v); }
__device__ __forceinline__ short f2s(float v) { bf16 h = f2b(v); return *(short*)&h; }
__device__ __forceinline__ float s2f(unsigned short s) {
    return __int_as_float(((int)s) << 16);
}
__device__ __forceinline__ float silu(float v) {
    return v * __builtin_amdgcn_rcpf(1.0f + __expf(-v));
}
__device__ __forceinline__ int isf_of(const int* flagp) {
    return (__int_as_float(flagp[0]) > 1.0e4f) ? 1 : 0;
}

template<int ISF>
__device__ __forceinline__ float LD(const void* p, size_t i) {
    if (ISF) return ((const float*)p)[i];
    return b2f(((const bf16*)p)[i]);
}

// 8 consecutive f32 -> bf8v via two dwordx4 loads (same rounding as scalar path)
__device__ __forceinline__ bf8v f32x8_to_b(const float* p) {
    f4v v0 = *(const f4v*)p;
    f4v v1 = *(const f4v*)(p + 4);
    bf8v r;
    r[0] = f2s(v0[0]); r[1] = f2s(v0[1]); r[2] = f2s(v0[2]); r[3] = f2s(v0[3]);
    r[4] = f2s(v1[0]); r[5] = f2s(v1[1]); r[6] = f2s(v1[2]); r[7] = f2s(v1[3]);
    return r;
}
template<int ISF>
__device__ __forceinline__ bf8v LD8(const void* p, size_t i) {
    if (ISF) return f32x8_to_b((const float*)p + i);
    return *(const bf8v*)((const bf16*)p + i);
}

__device__ __forceinline__ int clampN(int v) {
    return v < 0 ? 0 : (v >= NATOMS ? NATOMS - 1 : v);
}

// edge distance (computed once, in histd; cached to d_raw for permgeom)
template<int ISF>
__device__ __forceinline__ float edge_d(const int* __restrict__ ei,
                                        const void* __restrict__ pos, int e,
                                        int* sOut, int* tOut) {
    int s = clampN(ei[e]);
    int t = clampN(ei[NEDGES + e]);
    *sOut = s; *tOut = t;
    float dx = LD<ISF>(pos, (size_t)s * 3 + 0) - LD<ISF>(pos, (size_t)t * 3 + 0);
    float dy = LD<ISF>(pos, (size_t)s * 3 + 1) - LD<ISF>(pos, (size_t)t * 3 + 1);
    float dz = LD<ISF>(pos, (size_t)s * 3 + 2) - LD<ISF>(pos, (size_t)t * 3 + 2);
    float d = sqrtf(dx * dx + dy * dy + dz * dz + 1e-12f);
    if (d != d) d = 1e30f;
    return d;
}

// ---------------- dtype probe ----------------
__global__ void probe_k(const void* pos, int* flag) {
    int i = blockIdx.x * 256 + threadIdx.x;
    float v = 0.0f;
    if (i < NATOMS * 3) {
        v = fabsf(b2f(((const bf16*)pos)[i]));
        if (v != v) v = 1e30f;
    }
    #pragma unroll
    for (int off = 32; off > 0; off >>= 1)
        v = fmaxf(v, __shfl_xor(v, off, 64));
    if ((threadIdx.x & 63) == 0) atomicMax(flag, __float_as_int(v));
}

// ------- histogram of ACTIVE (d<5) edges + d cache -------
template<int ISF>
__device__ __forceinline__ void histd_body(int b, int tid, const int* __restrict__ ei,
                                           const void* __restrict__ pos,
                                           int* __restrict__ counts,
                                           float* __restrict__ d_raw) {
    int e = b * 256 + tid;
    if (e >= NEDGES) return;
    int s, t;
    float d = edge_d<ISF>(ei, pos, e, &s, &t);
    d_raw[e] = d;            // cache for permgeom (bit-identical d)
    if (d < 5.0f) atomicAdd(&counts[t], 1);
}

// ---------------- mega pack/convert ----------------
template<int ISF>
__device__ void packB_at(int t, const void* src, int K, int ksteps, size_t perLsrc,
                         size_t perLdst, int L, bf16* dst) {
    if (t >= L * 8 * ksteps * 64) return;
    int lane = t & 63;
    int t2 = t >> 6;
    int ks = t2 % ksteps;
    int t3 = t2 / ksteps;
    int nt = t3 & 7;
    int l  = t3 >> 3;
    int quad = lane >> 4, lc = lane & 15;
    int col = nt * 16 + lc;
    for (int j = 0; j < 8; j++) {
        int k = ks * 32 + quad * 8 + j;
        float v = (k < K) ? LD<ISF>(src, (size_t)l * perLsrc + (size_t)k * 128 + col) : 0.0f;
        dst[(size_t)l * perLdst + ((size_t)((nt * ksteps + ks) * 64 + lane)) * 8 + j] = f2b(v);
    }
}
template<int ISF>
__device__ void packB24_at(int t, const void* w2, const void* cw1, const void* cw2,
                           const void* lw, bf16* w2p, bf16* cw1p, bf16* cw2p, bf16* lwp) {
    if (t >= 24 * 8 * 4 * 64) return;
    int lane = t & 63;
    int t2 = t >> 6;
    int ks = t2 & 3;
    int t3 = t2 >> 2;
    int nt = t3 & 7;
    int m  = t3 >> 3;
    int which = m / NLAY, li = m % NLAY;
    const void* src = which == 0 ? w2 : which == 1 ? cw1 : which == 2 ? cw2 : lw;
    bf16* dst = which == 0 ? w2p : which == 1 ? cw1p : which == 2 ? cw2p : lwp;
    int quad = lane >> 4, lc = lane & 15;
    int col = nt * 16 + lc;
    #pragma unroll
    for (int j = 0; j < 8; j++) {
        int k = ks * 32 + quad * 8 + j;
        float v = LD<ISF>(src, (size_t)li * 16384 + (size_t)k * 128 + col);
        dst[(size_t)li * 16384 + ((size_t)((nt * 4 + ks) * 64 + lane)) * 8 + j] = f2b(v);
    }
}
template<int ISF>
__device__ void cvts_at(int i, const void* means, const void* betas, const void* bp,
                        const void* bc, const void* b1, const void* b2,
                        const void* cb2, const void* lb,
                        float* meanscv, float* betascv, float* bpcv, float* bccv,
                        float* b1cv, float* b2cv, float* cb2cv, float* lbcv) {
    if      (i < 50)   meanscv[i]        = LD<ISF>(means, i);
    else if (i < 100)  betascv[i - 50]   = LD<ISF>(betas, i - 50);
    else if (i < 228)  bpcv[i - 100]     = LD<ISF>(bp, i - 100);
    else if (i < 356)  bccv[i - 228]     = LD<ISF>(bc, i - 228);
    else if (i < 1124) b1cv[i - 356]     = LD<ISF>(b1, i - 356);
    else if (i < 1892) b2cv[i - 1124]    = LD<ISF>(b2, i - 1124);
    else if (i < 2660) cb2cv[i - 1892]   = LD<ISF>(cb2, i - 1892);
    else if (i < 3428) lbcv[i - 2660]    = LD<ISF>(lb, i - 2660);
}
template<int ISF>
__device__ void packall_body(int b, int tid, const void* Wp, const void* Wc, const void* W1,
                             const void* W2, const void* cW1, const void* cW2,
                             const void* lW, const void* means, const void* betas,
                             const void* bp, const void* bc, const void* b1,
                             const void* b2, const void* cb2, const void* lb,
                             const void* nbremb,
                             bf16* wpp, bf16* wcp, bf16* w1p, bf16* w2p, bf16* cw1p,
                             bf16* cw2p, bf16* lwp, float* meanscv, float* betascv,
                             float* bpcv, float* bccv, float* b1cv, float* b2cv,
                             float* cb2cv, float* lbcv, bf16* nbrembbf) {
    if (b < 4)        packB_at<ISF>(b * 256 + tid, Wp, RBF, 2, 6400, 8192, 1, wpp);
    else if (b < 20)  packB_at<ISF>((b - 4) * 256 + tid, Wc, 256, 8, 32768, 32768, 1, wcp);
    else if (b < 44)  packB_at<ISF>((b - 20) * 256 + tid, W1, RBF, 2, 6400, 8192, NLAY, w1p);
    else if (b < 236) packB24_at<ISF>((b - 44) * 256 + tid, W2, cW1, cW2, lW,
                                      w2p, cw1p, cw2p, lwp);
    else if (b < 250) cvts_at<ISF>((b - 236) * 256 + tid, means, betas, bp, bc, b1, b2,
                                   cb2, lb, meanscv, betascv, bpcv, bccv,
                                   b1cv, b2cv, cb2cv, lbcv);
    else {
        int i = (b - 250) * 256 + tid;
        if (i < MAXZ_ * HC) nbrembbf[i] = f2b(LD<ISF>(nbremb, i));
    }
}

// -------- setup1: histd (blocks 0..1249) + packall (blocks 1250..1549) --------
__global__ __launch_bounds__(256)
void setup1_k(const int* ei, const void* pos, const int* flagp,
              int* counts, float* d_raw,
              const void* Wp, const void* Wc, const void* W1,
              const void* W2, const void* cW1, const void* cW2,
              const void* lW, const void* means, const void* betas,
              const void* bp, const void* bc, const void* b1,
              const void* b2, const void* cb2, const void* lb,
              const void* nbremb,
              bf16* wpp, bf16* wcp, bf16* w1p, bf16* w2p, bf16* cw1p,
              bf16* cw2p, bf16* lwp, float* meanscv, float* betascv,
              float* bpcv, float* bccv, float* b1cv, float* b2cv,
              float* cb2cv, float* lbcv, bf16* nbrembbf) {
    int b = blockIdx.x, tid = threadIdx.x;
    int isf = isf_of(flagp);
    if (b < EG) {
        if (isf) histd_body<1>(b, tid, ei, pos, counts, d_raw);
        else     histd_body<0>(b, tid, ei, pos, counts, d_raw);
    } else {
        b -= EG;
        if (isf) packall_body<1>(b, tid, Wp, Wc, W1, W2, cW1, cW2, lW, means, betas,
                                 bp, bc, b1, b2, cb2, lb, nbremb, wpp, wcp,
                                 w1p, w2p, cw1p, cw2p, lwp, meanscv, betascv,
                                 bpcv, bccv, b1cv, b2cv, cb2cv, lbcv, nbrembbf);
        else     packall_body<0>(b, tid, Wp, Wc, W1, W2, cW1, cW2, lW, means, betas,
                                 bp, bc, b1, b2, cb2, lb, nbremb, wpp, wcp,
                                 w1p, w2p, cw1p, cw2p, lwp, meanscv, betascv,
                                 bpcv, bccv, b1cv, b2cv, cb2cv, lbcv, nbrembbf);
    }
}

// ---------------- scan (one-pass: 10 elems/thread) ----------------
__global__ void scan_k(const int* __restrict__ counts, int* __restrict__ rowptr,
                       int* __restrict__ cursor) {
    __shared__ int wsum[16];
    int tid = threadIdx.x, lane = tid & 63, w = tid >> 6;
    int base = tid * 10;
    int v[10];
    int s = 0;
    #pragma unroll
    for (int j = 0; j < 10; j++) {
        int i = base + j;
        int c = (i < NATOMS) ? counts[i] : 0;
        v[j] = c; s += c;
    }
    int si = s;
    #pragma unroll
    for (int off = 1; off < 64; off <<= 1) {
        int t = __shfl_up(si, off, 64);
        if (lane >= off) si += t;
    }
    if (lane == 63) wsum[w] = si;
    __syncthreads();
    if (w == 0 && lane < 16) {
        int t = wsum[lane];
        int s2 = t;
        #pragma unroll
        for (int off = 1; off < 16; off <<= 1) {
            int u = __shfl_up(s2, off, 64);
            if (lane >= off) s2 += u;
        }
        wsum[lane] = s2 - t;   // exclusive wave prefix
    }
    __syncthreads();
    int run = wsum[w] + si - s;   // exclusive prefix of this thread's chunk
    #pragma unroll
    for (int j = 0; j < 10; j++) {
        int i = base + j;
        if (i < NATOMS) {
            cursor[i] = run;
            run += v[j];
            rowptr[i + 1] = run;
        }
    }
    if (tid == 0) rowptr[0] = 0;
}

// ---------------- MFMA helpers ----------------
#define MFMA(a, b, c) __builtin_amdgcn_mfma_f32_16x16x32_bf16((a), (b), (c), 0, 0, 0)

// ---------- permgeom body (blocks 0..1249 of setup2) ----------
__device__ __forceinline__ void permgeom_body(int b, int tid, const int* __restrict__ ei,
                                              const float* __restrict__ d_raw,
                                              int* __restrict__ cursor,
                                              int* __restrict__ kidx_s,
                                              int* __restrict__ src_s,
                                              int* __restrict__ dst_s) {
    int e = b * 256 + tid;
    if (e >= NEDGES) return;
    float d = d_raw[e];
    if (d >= 5.0f) return;                  // dead edge: exactly 0 contribution
    int s = clampN(ei[e]);
    int t = clampN(ei[NEDGES + e]);
    int p = atomicAdd(&cursor[t], 1);
    float ed = __expf(-d);
    float pos = fminf(fmaxf(ed * (float)(NK - 1) + 0.5f, 0.0f), (float)(NK - 1));
    kidx_s[p] = (int)pos;
    src_s[p] = s;
    dst_s[p] = t;
}

// ---------- tabbuild body (blocks 1250.. of setup2) ----------
__device__ __forceinline__ void tabbuild_body(int bb, int tid,
                const bf16* __restrict__ wpp, const float* __restrict__ bpcv,
                const bf16* __restrict__ w1p, const float* __restrict__ b1cv,
                const bf16* __restrict__ w2p, const float* __restrict__ b2cv,
                const float* __restrict__ meanscv, const float* __restrict__ betascv,
                bf16* __restrict__ Tb) {
    __shared__ bf16 hid[64][136];
    __shared__ float csh[64], edsh[64];
    int f = bb / KB_F, kb = bb % KB_F;
    int base = kb * 64;
    int wave = tid >> 6, lane = tid & 63, quad = lane >> 4, lc = lane & 15;
    if (tid < 64) {
        float ed = (float)(base + tid) * (1.0f / (NK - 1));
        float d = -logf(fmaxf(ed, 1e-30f));
        float C = (d < 5.0f) ? 0.5f * (__cosf(d * 0.6283185307f) + 1.0f) : 0.0f;
        csh[tid] = C; edsh[tid] = ed;
    }
    __syncthreads();
    float edi = edsh[wave * 16 + lc], Ci = csh[wave * 16 + lc];
    bf8v af[2];
    #pragma unroll
    for (int ks = 0; ks < 2; ks++) {
        #pragma unroll
        for (int j = 0; j < 8; j++) {
            int r = ks * 32 + quad * 8 + j;
            float v = 0.0f;
            if (r < RBF) { float u = edi - meanscv[r]; v = Ci * __expf(-betascv[r] * u * u); }
            af[ks][j] = f2s(v);
        }
    }
    f4v zero = {0.f, 0.f, 0.f, 0.f};
    f4v acc[8];
    #pragma unroll
    for (int nt = 0; nt < 8; nt++) acc[nt] = zero;
    const bf16* w1b = (f == 0) ? wpp : w1p + (size_t)(f - 1) * 8192;
    #pragma unroll
    for (int nt = 0; nt < 8; nt++)
        #pragma unroll
        for (int ks = 0; ks < 2; ks++) {
            bf8v b = *(const bf8v*)(w1b + ((nt * 2 + ks) * 64 + lane) * 8);
            acc[nt] = MFMA(af[ks], b, acc[nt]);
        }
    if (f == 0) {
        #pragma unroll
        for (int nt = 0; nt < 8; nt++) {
            int n = nt * 16 + lc;
            float bb2 = bpcv[n];
            #pragma unroll
            for (int r = 0; r < 4; r++) {
                int row = wave * 16 + quad * 4 + r;
                Tb[(size_t)(base + row) * HC + n] = f2b((acc[nt][r] + bb2) * csh[row]);
            }
        }
        return;
    }
    int l = f - 1;
    #pragma unroll
    for (int nt = 0; nt < 8; nt++) {
        int n = nt * 16 + lc;
        float bb2 = b1cv[l * HC + n];
        #pragma unroll
        for (int r = 0; r < 4; r++)
            hid[wave * 16 + quad * 4 + r][n] = f2b(silu(acc[nt][r] + bb2));
    }
    __syncthreads();
    bf8v a2[4];
    #pragma unroll
    for (int ks = 0; ks < 4; ks++)
        a2[ks] = *(const bf8v*)&hid[wave * 16 + lc][ks * 32 + quad * 8];
    f4v acc2[8];
    #pragma unroll
    for (int nt = 0; nt < 8; nt++) acc2[nt] = zero;
    const bf16* w2b = w2p + (size_t)l * 16384;
    #pragma unroll
    for (int nt = 0; nt < 8; nt++)
        #pragma unroll
        for (int ks = 0; ks < 4; ks++) {
            bf8v b = *(const bf8v*)(w2b + ((nt * 4 + ks) * 64 + lane) * 8);
            acc2[nt] = MFMA(a2[ks], b, acc2[nt]);
        }
    #pragma unroll
    for (int nt = 0; nt < 8; nt++) {
        int n = nt * 16 + lc;
        float bb2 = b2cv[l * HC + n];
        #pragma unroll
        for (int r = 0; r < 4; r++) {
            int row = wave * 16 + quad * 4 + r;
            Tb[((size_t)f * NK + base + row) * HC + n] = f2b((acc2[nt][r] + bb2) * csh[row]);
        }
    }
}

// -------- setup2: permgeom (blocks 0..1249) + tabbuild (blocks 1250..) --------
__global__ __launch_bounds__(256)
void setup2_k(const int* ei, const float* d_raw, int* cursor,
              int* kidx_s, int* src_s, int* dst_s,
              const bf16* wpp, const float* bpcv,
              const bf16* w1p, const float* b1cv,
              const bf16* w2p, const float* b2cv,
              const float* meanscv, const float* betascv, bf16* Tb) {
    int b = blockIdx.x, tid = threadIdx.x;
    if (b < EG) permgeom_body(b, tid, ei, d_raw, cursor, kidx_s, src_s, dst_s);
    else        tabbuild_body(b - EG, tid, wpp, bpcv, w1p, b1cv, w2p, b2cv,
                              meanscv, betascv, Tb);
}

// ---------------- segment helpers ----------------
__device__ __forceinline__ void seg_prep(const int* __restrict__ dst_s, int i0, int tid,
                                         int* ddst, int* slot_s, int* distinct_s,
                                         int* nseg_s) {
    if (tid < 64) {
        int d = dst_s[i0 + tid];
        ddst[tid] = d;
        int dprev = __shfl_up(d, 1, 64);
        int flag = (tid == 0 || d != dprev) ? 1 : 0;
        int s = flag;
        #pragma unroll
        for (int off = 1; off < 64; off <<= 1) {
            int t = __shfl_up(s, off, 64);
            if (tid >= off) s += t;
        }
        slot_s[tid] = s - 1;
        if (flag) distinct_s[s - 1] = d;
        if (tid == 63) *nseg_s = s;
    }
}

__device__ __forceinline__ void seg_mfma(const bf16 (*mvT)[72], const int* ddst,
                                         const int* slot_s, const int* distinct_s,
                                         int nseg, float* __restrict__ out, int tid) {
    int wave = tid >> 6, lane = tid & 63, quad = lane >> 4, lc = lane & 15;
    if (nseg <= 16) {
        bf8v sa[2];
        #pragma unroll
        for (int ks = 0; ks < 2; ks++) {
            int k0 = ks * 32 + quad * 8;
            i4v s0 = *(const i4v*)&slot_s[k0];
            i4v s1 = *(const i4v*)&slot_s[k0 + 4];
            #pragma unroll
            for (int j = 0; j < 4; j++) {
                sa[ks][j]     = (s0[j] == lc) ? (short)0x3F80 : (short)0;
                sa[ks][j + 4] = (s1[j] == lc) ? (short)0x3F80 : (short)0;
            }
        }
        f4v z4 = {0.f, 0.f, 0.f, 0.f};
        f4v sacc[2] = {z4, z4};
        #pragma unroll
        for (int nt = 0; nt < 2; nt++)
            #pragma unroll
            for (int ks = 0; ks < 2; ks++) {
                bf8v b = *(const bf8v*)&mvT[wave * 32 + nt * 16 + lc][ks * 32 + quad * 8];
                sacc[nt] = MFMA(sa[ks], b, sacc[nt]);
            }
        #pragma unroll
        for (int nt = 0; nt < 2; nt++)
            #pragma unroll
            for (int r = 0; r < 4; r++) {
                int sl = quad * 4 + r;
                if (sl < nseg) {
                    int atom = distinct_s[sl];
                    int n = wave * 32 + nt * 16 + lc;
                    float v = sacc[nt][r];
                    if (sl == 0 || sl == nseg - 1)
                        atomicAdd(&out[(size_t)atom * HC + n], v);
                    else
                        out[(size_t)atom * HC + n] = v;
                }
            }
    } else {
        int col = tid & 127;
        int base = (tid >> 7) * 32;
        int cur = ddst[base];
        float s = 0.0f;
        bool first = true;
        for (int e = base; e < base + 32; e++) {
            int dn = ddst[e];
            if (dn != cur) {
                if (first) atomicAdd(&out[(size_t)cur * HC + col], s);
                else out[(size_t)cur * HC + col] = s;
                first = false; cur = dn; s = 0.0f;
            }
            s += b2f(mvT[col][e]);
        }
        atomicAdd(&out[(size_t)cur * HC + col], s);
    }
}

// ---------------- neighbor edges ----------------
__global__ __launch_bounds__(256)
void nbr_tab_k(const int* __restrict__ rowptr,
               const int* __restrict__ kidx_s, const int* __restrict__ src_s,
               const int* __restrict__ dst_s, const int* __restrict__ z,
               const bf16* __restrict__ nbrembbf, const bf16* __restrict__ Tb,
               float* __restrict__ msg) {
    __shared__ bf16 mvT[128][72];
    __shared__ int ddst[64], slot_s[64], distinct_s[64];
    __shared__ int nseg_s;
    int i0 = blockIdx.x * 64;
    if (i0 >= rowptr[NATOMS]) return;
    int tid = threadIdx.x;
    seg_prep(dst_s, i0, tid, ddst, slot_s, distinct_s, &nseg_s);
    int row = tid & 63, c0 = (tid >> 6) * 32;
    int e = i0 + row;
    int s = src_s[e];
    float msk = (s != dst_s[e]) ? 1.0f : 0.0f;
    int k = kidx_s[e];
    const bf8v* tp = (const bf8v*)(Tb + (size_t)k * HC + c0);
    bf8v tv[4];
    #pragma unroll
    for (int g = 0; g < 4; g++) tv[g] = tp[g];
    int zz = z[s]; zz = zz < 0 ? 0 : (zz >= MAXZ_ ? MAXZ_ - 1 : zz);
    const bf8v* ep = (const bf8v*)(nbrembbf + (size_t)zz * HC + c0);
    bf8v ev[4];
    #pragma unroll
    for (int g = 0; g < 4; g++) ev[g] = ep[g];
    #pragma unroll
    for (int g = 0; g < 4; g++)
        #pragma unroll
        for (int m = 0; m < 8; m++) {
            float v = s2f((unsigned short)tv[g][m]) * msk *
                      s2f((unsigned short)ev[g][m]);
            mvT[c0 + g * 8 + m][row] = f2b(v);
        }
    __syncthreads();
    seg_mfma(mvT, ddst, slot_s, distinct_s, nseg_s, msg, tid);
}

// ---------------- combine (prep fused) ----------------
template<int ISF>
__device__ void combine_body(const int* __restrict__ z, const void* __restrict__ emb,
                             const float* __restrict__ msg, const bf16* __restrict__ wcp,
                             const float* __restrict__ bccv, const bf16* __restrict__ cw1b,
                             float* __restrict__ x, bf16* __restrict__ xb,
                             bf16* __restrict__ ybf) {
    __shared__ bf16 srow[64][136];
    int tid = threadIdx.x;
    int wave = tid >> 6, lane = tid & 63, quad = lane >> 4, lc = lane & 15;
    int m0 = blockIdx.x * 64;
    int arow = m0 + wave * 16 + lc;
    int rowc = arow < NATOMS ? arow : NATOMS - 1;
    int zz = z[rowc]; zz = zz < 0 ? 0 : (zz >= MAXZ_ ? MAXZ_ - 1 : zz);
    bf8v af[8];
    #pragma unroll
    for (int ks = 0; ks < 4; ks++)
        af[ks] = LD8<ISF>(emb, (size_t)zz * HC + ks * 32 + quad * 8);
    #pragma unroll
    for (int ks = 4; ks < 8; ks++)
        af[ks] = f32x8_to_b(msg + (size_t)rowc * HC + (ks - 4) * 32 + quad * 8);
    f4v zero = {0.f, 0.f, 0.f, 0.f};
    f4v acc[8];
    #pragma unroll
    for (int nt = 0; nt < 8; nt++) acc[nt] = zero;
    #pragma unroll
    for (int nt = 0; nt < 8; nt++)
        #pragma unroll
        for (int ks = 0; ks < 8; ks++) {
            bf8v b = *(const bf8v*)(wcp + ((nt * 8 + ks) * 64 + lane) * 8);
            acc[nt] = MFMA(af[ks], b, acc[nt]);
        }
    #pragma unroll
    for (int nt = 0; nt < 8; nt++) {
        int n = nt * 16 + lc;
        float bb = bccv[n];
        #pragma unroll
        for (int r = 0; r < 4; r++) {
            int row = m0 + wave * 16 + quad * 4 + r;
            float v = acc[nt][r] + bb;
            bf16 vb = f2b(v);
            srow[wave * 16 + quad * 4 + r][n] = vb;
            if (row < NATOMS) {
                x[(size_t)row * HC + n] = v;
                xb[(size_t)row * HC + n] = vb;
            }
        }
    }
    __syncthreads();
    bf8v a3[4];
    #pragma unroll
    for (int ks = 0; ks < 4; ks++)
        a3[ks] = *(const bf8v*)&srow[wave * 16 + lc][ks * 32 + quad * 8];
    f4v acc3[8];
    #pragma unroll
    for (int nt = 0; nt < 8; nt++) acc3[nt] = zero;
    #pragma unroll
    for (int nt = 0; nt < 8; nt++)
        #pragma unroll
        for (int ks = 0; ks < 4; ks++) {
            bf8v b = *(const bf8v*)(cw1b + ((nt * 4 + ks) * 64 + lane) * 8);
            acc3[nt] = MFMA(a3[ks], b, acc3[nt]);
        }
    #pragma unroll
    for (int nt = 0; nt < 8; nt++) {
        int n = nt * 16 + lc;
        #pragma unroll
        for (int r = 0; r < 4; r++) {
            int row = m0 + wave * 16 + quad * 4 + r;
            if (row < NATOMS) ybf[(size_t)row * HC + n] = f2b(acc3[nt][r]);
        }
    }
}
__global__ __launch_bounds__(256)
void combine_k(const int* z, const void* emb, const float* msg, const bf16* wcp,
               const float* bccv, const bf16* cw1b, const int* flagp,
               float* x, bf16* xb, bf16* ybf) {
    if (isf_of(flagp)) combine_body<1>(z, emb, msg, wcp, bccv, cw1b, x, xb, ybf);
    else               combine_body<0>(z, emb, msg, wcp, bccv, cw1b, x, xb, ybf);
}

// ---------------- filter edges ----------------
__global__ __launch_bounds__(256)
void filt_tab_k(int l, const int* __restrict__ rowptr,
                const int* __restrict__ kidx_s, const int* __restrict__ src_s,
                const int* __restrict__ dst_s, const bf16* __restrict__ ybf,
                const bf16* __restrict__ Tb, float* __restrict__ msum) {
    __shared__ bf16 mvT[128][72];
    __shared__ int ddst[64], slot_s[64], distinct_s[64];
    __shared__ int nseg_s;
    int i0 = blockIdx.x * 64;
    if (i0 >= rowptr[NATOMS]) return;
    int tid = threadIdx.x;
    seg_prep(dst_s, i0, tid, ddst, slot_s, distinct_s, &nseg_s);
    int row = tid & 63, c0 = (tid >> 6) * 32;
    int e = i0 + row;
    int k = kidx_s[e];
    const bf8v* tp = (const bf8v*)(Tb + ((size_t)(l + 1) * NK + k) * HC + c0);
    bf8v tv[4];
    #pragma unroll
    for (int g = 0; g < 4; g++) tv[g] = tp[g];
    const bf8v* yp = (const bf8v*)(ybf + (size_t)src_s[e] * HC + c0);
    bf8v yv[4];
    #pragma unroll
    for (int g = 0; g < 4; g++) yv[g] = yp[g];
    #pragma unroll
    for (int g = 0; g < 4; g++)
        #pragma unroll
        for (int m = 0; m < 8; m++) {
            float v = s2f((unsigned short)tv[g][m]) * s2f((unsigned short)yv[g][m]);
            mvT[c0 + g * 8 + m][row] = f2b(v);
        }
    __syncthreads();
    seg_mfma(mvT, ddst, slot_s, distinct_s, nseg_s, msum, tid);
}

// ---- node update, 16 rows/block (625 blocks for TLP) ----
__global__ __launch_bounds__(256)
void upd_mfma_k(float* msum, int l,
                const bf16* __restrict__ cw2p, const float* __restrict__ cb2cv,
                const bf16* __restrict__ lwp, const float* __restrict__ lbcv,
                const bf16* __restrict__ cw1p, int do_y, int last,
                float* __restrict__ x, bf16* __restrict__ xb,
                bf16* __restrict__ ybf, void* out, const int* flagp) {
    __shared__ bf16 srow[16][136];
    int tid = threadIdx.x;
    int w = tid >> 6, lane = tid & 63, quad = lane >> 4, lc = lane & 15;
    int m0 = blockIdx.x * 16;     // NATOMS % 16 == 0 -> no row guards
    bf8v af[4];
    #pragma unroll
    for (int ks = 0; ks < 4; ks++)
        af[ks] = f32x8_to_b(msum + (size_t)(m0 + lc) * HC + ks * 32 + quad * 8);
    f4v zero = {0.f, 0.f, 0.f, 0.f};
    f4v acc[2] = {zero, zero};
    const bf16* c2b = cw2p + (size_t)l * 16384;
    #pragma unroll
    for (int nt = 0; nt < 2; nt++)
        #pragma unroll
        for (int ks = 0; ks < 4; ks++) {
            bf8v b = *(const bf8v*)(c2b + (((w * 2 + nt) * 4 + ks) * 64 + lane) * 8);
            acc[nt] = MFMA(af[ks], b, acc[nt]);
        }
    #pragma unroll
    for (int nt = 0; nt < 2; nt++) {
        int n = w * 32 + nt * 16 + lc;
        float bb = cb2cv[l * HC + n];
        #pragma unroll
        for (int r = 0; r < 4; r++)
            srow[quad * 4 + r][n] = f2b(silu(acc[nt][r] + bb));
    }
    __syncthreads();   // af loads drained before re-zero (barrier = memory fence)
    // re-zero this block's msum rows for the next layer's scatter
    {
        int zr = tid >> 4, zc = (tid & 15) * 8;
        *(f4v*)(msum + (size_t)(m0 + zr) * HC + zc) = zero;
        *(f4v*)(msum + (size_t)(m0 + zr) * HC + zc + 4) = zero;
    }
    bf8v a2[4];
    #pragma unroll
    for (int ks = 0; ks < 4; ks++)
        a2[ks] = *(const bf8v*)&srow[lc][ks * 32 + quad * 8];
    __syncthreads();   // srow reused for nv below
    f4v acc2[2] = {zero, zero};
    const bf16* lwb = lwp + (size_t)l * 16384;
    #pragma unroll
    for (int nt = 0; nt < 2; nt++)
        #pragma unroll
        for (int ks = 0; ks < 4; ks++) {
            bf8v b = *(const bf8v*)(lwb + (((w * 2 + nt) * 4 + ks) * 64 + lane) * 8);
            acc2[nt] = MFMA(a2[ks], b, acc2[nt]);
        }
    int isf = isf_of(flagp);
    #pragma unroll
    for (int nt = 0; nt < 2; nt++) {
        int n = w * 32 + nt * 16 + lc;
        float bb = lbcv[l * HC + n];
        #pragma unroll
        for (int r = 0; r < 4; r++) {
            int row = m0 + quad * 4 + r;
            size_t o = (size_t)row * HC + n;
            float nv = x[o] + acc2[nt][r] + bb;
            if (!last) {
                x[o] = nv;
                xb[o] = f2b(nv);
            } else {
                if (isf) ((float*)out)[o] = nv;
                else     ((bf16*)out)[o] = f2b(nv);
            }
            srow[quad * 4 + r][n] = f2b(nv);
        }
    }
    if (do_y) {
        __syncthreads();
        bf8v a3[4];
        #pragma unroll
        for (int ks = 0; ks < 4; ks++)
            a3[ks] = *(const bf8v*)&srow[lc][ks * 32 + quad * 8];
        f4v acc3[2] = {zero, zero};
        const bf16* c1b = cw1p + (size_t)(l + 1) * 16384;
        #pragma unroll
        for (int nt = 0; nt < 2; nt++)
            #pragma unroll
            for (int ks = 0; ks < 4; ks++) {
                bf8v b = *(const bf8v*)(c1b + (((w * 2 + nt) * 4 + ks) * 64 + lane) * 8);
                acc3[nt] = MFMA(a3[ks], b, acc3[nt]);
            }
        #pragma unroll
        for (int nt = 0; nt < 2; nt++) {
            int n = w * 32 + nt * 16 + lc;
            #pragma unroll
            for (int r = 0; r < 4; r++) {
                int row = m0 + quad * 4 + r;
                ybf[(size_t)row * HC + n] = f2b(acc3[nt][r]);
            }
        }
    }
}

// ---------------- launch ----------------
extern "C" void kernel_launch(void* const* d_in, const int* in_sizes, int n_in,
                              void* d_out, int out_size, void* d_ws, size_t ws_size,
                              hipStream_t stream) {
    const int*  z      = (const int*) d_in[0];
    const void* pos    = d_in[1];
    const int*  ei     = (const int*) d_in[3];
    const void* emb    = d_in[4];
    const void* nbremb = d_in[5];
    const void* Wp     = d_in[6];
    const void* bp     = d_in[7];
    const void* Wc     = d_in[8];
    const void* bc     = d_in[9];
    const void* means  = d_in[10];
    const void* betas  = d_in[11];
    const void* W1     = d_in[12];
    const void* b1     = d_in[13];
    const void* W2     = d_in[14];
    const void* b2     = d_in[15];
    const void* cW1    = d_in[16];
    const void* cW2    = d_in[17];
    const void* cb2    = d_in[18];
    const void* lW     = d_in[19];
    const void* lb     = d_in[20];

    char* p = (char*)d_ws;
    auto alloc = [&](size_t bytes) { char* r = p; p += (bytes + 255) / 256 * 256; return r; };
    // flag | counts | msum | msg | kidx | src_s | dst_s CONTIGUOUS -> one memset
    // zeroes pads too (pad edge: kidx=0 -> Tb row 0 (=0), src=0, dst=0; pads are a
    // suffix of any 64-edge window -> always first/last segment -> atomicAdd(+0.0)).
    int*   flag    = (int*)  alloc(256);
    int*   counts  = (int*)  alloc((size_t)NATOMS * 4);
    float* msum    = (float*)alloc((size_t)NATOMS * HC * 4);
    float* msg     = (float*)alloc((size_t)NATOMS * HC * 4);
    int*   kidx_s  = (int*)  alloc((size_t)NEDGES * 4);
    int*   src_s   = (int*)  alloc((size_t)NEDGES * 4);
    int*   dst_s   = (int*)  alloc((size_t)NEDGES * 4);
    char*  zend    = p;
    int*   rowptr  = (int*)  alloc((size_t)(NATOMS + 1) * 4);
    int*   cursor  = (int*)  alloc((size_t)NATOMS * 4);
    float* d_raw   = (float*)alloc((size_t)NEDGES * 4);
    float* x       = (float*)alloc((size_t)NATOMS * HC * 4);
    bf16*  xb      = (bf16*) alloc((size_t)NATOMS * HC * 2);
    bf16*  ybf     = (bf16*) alloc((size_t)NATOMS * HC * 2);
    bf16*  Tb      = (bf16*) alloc((size_t)(NLAY + 1) * NK * HC * 2);  // 7.3 MB
    bf16*  wpp     = (bf16*) alloc((size_t)8192 * 2);
    bf16*  wcp     = (bf16*) alloc((size_t)32768 * 2);
    bf16*  w1p     = (bf16*) alloc((size_t)NLAY * 8192 * 2);
    bf16*  w2p     = (bf16*) alloc((size_t)NLAY * 16384 * 2);
    bf16*  cw1p    = (bf16*) alloc((size_t)NLAY * 16384 * 2);
    bf16*  cw2p    = (bf16*) alloc((size_t)NLAY * 16384 * 2);
    bf16*  lwp     = (bf16*) alloc((size_t)NLAY * 16384 * 2);
    bf16*  nbrembbf= (bf16*) alloc((size_t)MAXZ_ * HC * 2);
    float* bpcv    = (float*)alloc((size_t)HC * 4);
    float* bccv    = (float*)alloc((size_t)HC * 4);
    float* b1cv    = (float*)alloc((size_t)NLAY * HC * 4);
    float* b2cv    = (float*)alloc((size_t)NLAY * HC * 4);
    float* cb2cv   = (float*)alloc((size_t)NLAY * HC * 4);
    float* lbcv    = (float*)alloc((size_t)NLAY * HC * 4);
    float* meanscv = (float*)alloc((size_t)RBF * 4);
    float* betascv = (float*)alloc((size_t)RBF * 4);

    hipMemsetAsync(flag, 0, (size_t)(zend - (char*)flag), stream);
    probe_k<<<(NATOMS * 3 + 255) / 256, 256, 0, stream>>>(pos, flag);

    setup1_k<<<EG + 300, 256, 0, stream>>>(ei, pos, flag, counts, d_raw,
                                           Wp, Wc, W1, W2, cW1, cW2, lW, means, betas,
                                           bp, bc, b1, b2, cb2, lb, nbremb,
                                           wpp, wcp, w1p, w2p, cw1p, cw2p, lwp,
                                           meanscv, betascv, bpcv, bccv, b1cv, b2cv,
                                           cb2cv, lbcv, nbrembbf);
    scan_k<<<1, 1024, 0, stream>>>(counts, rowptr, cursor);
    setup2_k<<<EG + TBGRID, 256, 0, stream>>>(ei, d_raw, cursor, kidx_s, src_s, dst_s,
                                              wpp, bpcv, w1p, b1cv, w2p, b2cv,
                                              meanscv, betascv, Tb);

    nbr_tab_k<<<EGRID, 256, 0, stream>>>(rowptr, kidx_s, src_s, dst_s, z, nbrembbf,
                                         Tb, msg);
    combine_k<<<YGRID, 256, 0, stream>>>(z, emb, msg, wcp, bccv, cw1p, flag, x, xb, ybf);

    for (int l = 0; l < NLAY; l++) {
        filt_tab_k<<<EGRID, 256, 0, stream>>>(l, rowptr, kidx_s, src_s, dst_s, ybf,
                                              Tb, msum);
        int lastl = (l == NLAY - 1) ? 1 : 0;
        upd_mfma_k<<<UGRID, 256, 0, stream>>>(msum, l, cw2p, cb2cv, lwp, lbcv,
                                              cw1p, lastl ? 0 : 1, lastl,
                                              x, xb, ybf, d_out, flag);
    }
}